// Round 4
// baseline (2363.584 us; speedup 1.0000x reference)
//
#include <hip/hip_runtime.h>
#include <math.h>

#define B_ 2
#define L_ 1024
#define D_ 768
#define NL_ 8
#define DI_ 1536
#define NS_ 16
#define DR_ 48
#define KC_ 4
#define EPS_ 1e-5f
#define M_ (B_*L_)   // 2048 rows
#define NC_ 16       // scan chunks
#define T_ 64        // chunk length (NC_*T_ == L_)
#define KS_ 16       // x_proj split-K factor
#define KCH_ (DI_/KS_)   // 96 per split

typedef short bf16x8 __attribute__((ext_vector_type(8)));
typedef float f32x4  __attribute__((ext_vector_type(4)));

// ---------------- fp32 -> bf16 (RNE) ---------------------------------------
__device__ __forceinline__ unsigned short f2bf(float f) {
    union { float f; unsigned int u; } v; v.f = f;
    unsigned int u = v.u;
    u += 0x7fffu + ((u >> 16) & 1u);
    return (unsigned short)(u >> 16);
}

__global__ void convert_bf16_kernel(const float* __restrict__ src,
                                    unsigned short* __restrict__ dst, int n) {
    int i = blockIdx.x * blockDim.x + threadIdx.x;
    if (i < n) dst[i] = f2bf(src[i]);
}

// ---------------- block reduction helper (256 threads = 4 waves) ------------
__device__ __forceinline__ float block_sum256(float v) {
    __shared__ float sb[4];
    #pragma unroll
    for (int o = 32; o > 0; o >>= 1) v += __shfl_down(v, o);
    if ((threadIdx.x & 63) == 0) sb[threadIdx.x >> 6] = v;
    __syncthreads();
    float r = sb[0] + sb[1] + sb[2] + sb[3];
    __syncthreads();
    return r;
}

// ---------------- init: xcur = x, res = 0 -----------------------------------
__global__ void init_kernel(const float* __restrict__ x,
                            float* __restrict__ xcur,
                            float* __restrict__ res, int n) {
    int i = blockIdx.x * blockDim.x + threadIdx.x;
    if (i < n) { xcur[i] = x[i]; res[i] = 0.f; }
}

// ---------------- fused residual-accumulate + LayerNorm (bf16 out) ----------
__global__ __launch_bounds__(256) void ln_res_kernel(
    const float* __restrict__ xcur, float* __restrict__ res,
    const float* __restrict__ w, const float* __restrict__ b,
    unsigned short* __restrict__ xn) {
    int row = blockIdx.x;
    int t = threadIdx.x;
    size_t base = (size_t)row * D_;
    float v0 = xcur[base + t];
    float v1 = xcur[base + t + 256];
    float v2 = xcur[base + t + 512];
    res[base + t]       += v0;
    res[base + t + 256] += v1;
    res[base + t + 512] += v2;
    float mu = block_sum256(v0 + v1 + v2) * (1.0f / D_);
    float d0 = v0 - mu, d1 = v1 - mu, d2 = v2 - mu;
    float var = block_sum256(d0 * d0 + d1 * d1 + d2 * d2) * (1.0f / D_);
    float rs = rsqrtf(var + EPS_);
    xn[base + t]       = f2bf(d0 * rs * w[t]       + b[t]);
    xn[base + t + 256] = f2bf(d1 * rs * w[t + 256] + b[t + 256]);
    xn[base + t + 512] = f2bf(d2 * rs * w[t + 512] + b[t + 512]);
}

// ---------------- final LN: out = LN(xcur + res) ----------------------------
__global__ __launch_bounds__(256) void final_ln_kernel(
    const float* __restrict__ xcur, const float* __restrict__ res,
    const float* __restrict__ w, const float* __restrict__ b,
    float* __restrict__ out) {
    int row = blockIdx.x;
    int t = threadIdx.x;
    size_t base = (size_t)row * D_;
    float v0 = xcur[base + t]       + res[base + t];
    float v1 = xcur[base + t + 256] + res[base + t + 256];
    float v2 = xcur[base + t + 512] + res[base + t + 512];
    float mu = block_sum256(v0 + v1 + v2) * (1.0f / D_);
    float d0 = v0 - mu, d1 = v1 - mu, d2 = v2 - mu;
    float var = block_sum256(d0 * d0 + d1 * d1 + d2 * d2) * (1.0f / D_);
    float rs = rsqrtf(var + EPS_);
    out[base + t]       = d0 * rs * w[t]       + b[t];
    out[base + t + 256] = d1 * rs * w[t + 256] + b[t + 256];
    out[base + t + 512] = d2 * rs * w[t + 512] + b[t + 512];
}

// ---------------- bf16 MFMA GEMM: C[M,N] = A[M,K] * W[N,K]^T ---------------
__global__ __launch_bounds__(256) void gemm_bf16_kernel(
    const unsigned short* __restrict__ A,   // M x K bf16 row-major
    const unsigned short* __restrict__ W,   // N x K bf16 row-major
    float* __restrict__ C, int M, int N, int K) {
    __shared__ unsigned short sA[128 * 32];
    __shared__ unsigned short sW[128 * 32];
    int bm = blockIdx.y * 128, bn = blockIdx.x * 128;
    int tid = threadIdx.x;
    int wave = tid >> 6, lane = tid & 63;
    int wrow = (wave & 1) * 64, wcol = (wave >> 1) * 64;
    int quad = lane >> 4, r16 = lane & 15;
    f32x4 acc[4][4];
    #pragma unroll
    for (int i = 0; i < 4; i++)
        #pragma unroll
        for (int j = 0; j < 4; j++)
            acc[i][j] = (f32x4){0.f, 0.f, 0.f, 0.f};

    int srow = tid >> 2;              // 0..63
    int scol = (tid & 3) * 8;         // 0,8,16,24
    for (int k0 = 0; k0 < K; k0 += 32) {
        *(uint4*)&sA[tid * 8] =
            *(const uint4*)&A[(size_t)(bm + srow) * K + k0 + scol];
        *(uint4*)&sA[2048 + tid * 8] =
            *(const uint4*)&A[(size_t)(bm + 64 + srow) * K + k0 + scol];
        *(uint4*)&sW[tid * 8] =
            *(const uint4*)&W[(size_t)(bn + srow) * K + k0 + scol];
        *(uint4*)&sW[2048 + tid * 8] =
            *(const uint4*)&W[(size_t)(bn + 64 + srow) * K + k0 + scol];
        __syncthreads();
        bf16x8 af[4], wf[4];
        #pragma unroll
        for (int i = 0; i < 4; i++)
            af[i] = *(const bf16x8*)&sA[(wrow + i * 16 + r16) * 32 + quad * 8];
        #pragma unroll
        for (int j = 0; j < 4; j++)
            wf[j] = *(const bf16x8*)&sW[(wcol + j * 16 + r16) * 32 + quad * 8];
        #pragma unroll
        for (int i = 0; i < 4; i++)
            #pragma unroll
            for (int j = 0; j < 4; j++)
                acc[i][j] = __builtin_amdgcn_mfma_f32_16x16x32_bf16(
                    af[i], wf[j], acc[i][j], 0, 0, 0);
        __syncthreads();
    }
    #pragma unroll
    for (int i = 0; i < 4; i++) {
        #pragma unroll
        for (int j = 0; j < 4; j++) {
            int col = bn + wcol + j * 16 + r16;
            #pragma unroll
            for (int reg = 0; reg < 4; reg++) {
                int row = bm + wrow + i * 16 + quad * 4 + reg;
                C[(size_t)row * N + col] = acc[i][j][reg];
            }
        }
    }
}

// ---------------- x_proj GEMM: Pb[ks][M][80] partials, bf16 MFMA, split-K ---
__global__ __launch_bounds__(256) void xproj_gemm_kernel(
    const unsigned short* __restrict__ A,   // M x DI bf16 (xcb)
    const unsigned short* __restrict__ W,   // 80 x DI bf16
    float* __restrict__ Pb) {               // KS x M x 80 partials
    __shared__ unsigned short sA[64 * 32];
    __shared__ unsigned short sW[80 * 32];
    int ks = blockIdx.x;
    int bm = blockIdx.y * 64;
    int tid = threadIdx.x;
    int wave = tid >> 6, lane = tid & 63;
    int quad = lane >> 4, r16 = lane & 15;
    f32x4 acc[5];
    #pragma unroll
    for (int j = 0; j < 5; j++) acc[j] = (f32x4){0.f, 0.f, 0.f, 0.f};
    int k0base = ks * KCH_;
    for (int kc = 0; kc < KCH_; kc += 32) {
        int k0 = k0base + kc;
        {
            int row = tid >> 2, off = (tid & 3) * 8;
            *(uint4*)&sA[row * 32 + off] =
                *(const uint4*)&A[(size_t)(bm + row) * DI_ + k0 + off];
            *(uint4*)&sW[row * 32 + off] =
                *(const uint4*)&W[(size_t)row * DI_ + k0 + off];
            if (tid < 64) {
                int c = 256 + tid;
                int row2 = c >> 2, off2 = (c & 3) * 8;
                *(uint4*)&sW[row2 * 32 + off2] =
                    *(const uint4*)&W[(size_t)row2 * DI_ + k0 + off2];
            }
        }
        __syncthreads();
        bf16x8 af = *(const bf16x8*)&sA[(wave * 16 + r16) * 32 + quad * 8];
        #pragma unroll
        for (int j = 0; j < 5; j++) {
            bf16x8 wf = *(const bf16x8*)&sW[(j * 16 + r16) * 32 + quad * 8];
            acc[j] = __builtin_amdgcn_mfma_f32_16x16x32_bf16(af, wf, acc[j], 0, 0, 0);
        }
        __syncthreads();
    }
    #pragma unroll
    for (int j = 0; j < 5; j++) {
        int col = j * 16 + r16;
        #pragma unroll
        for (int reg = 0; reg < 4; reg++) {
            int row = bm + wave * 16 + quad * 4 + reg;
            Pb[((size_t)ks * M_ + row) * 80 + col] = acc[j][reg];
        }
    }
}

// reduce split-K partials; scatter into dbcdt (M x 48) and packed BC (M x 16 float2)
__global__ void xproj_reduce_kernel(const float* __restrict__ Pb,
                                    float* __restrict__ dbcdt,
                                    float* __restrict__ bcp) {
    int i = blockIdx.x * 256 + threadIdx.x;   // over M_*80
    float s = 0.f;
    #pragma unroll
    for (int ks = 0; ks < KS_; ks++) s += Pb[(size_t)ks * (M_ * 80) + i];
    int m = i / 80, col = i % 80;
    if (col < DR_) {
        dbcdt[m * DR_ + col] = s;
    } else if (col < DR_ + NS_) {
        bcp[m * 32 + 2 * (col - DR_)] = s;         // B_n
    } else {
        bcp[m * 32 + 2 * (col - DR_ - NS_) + 1] = s; // C_n
    }
}

// ---------------- dt GEMM (fp32, K=48): writes dt into dtxc[...].x ----------
__global__ __launch_bounds__(256) void dt_gemm_kernel(
    const float* __restrict__ A,          // M x 48 (dbcdt)
    const float* __restrict__ W,          // DI x 48 (dt_w)
    const float* __restrict__ bias,       // DI (dt_b)
    float* __restrict__ dtxc) {           // M x DI x 2, writes slot .x
    const int BM = 64, BN = 64, BK = 16;
    __shared__ float sA[BK][BM + 1];
    __shared__ float sW[BK][BN + 1];
    int bm = blockIdx.y * BM, bn = blockIdx.x * BN;
    int tid = threadIdx.x;
    int tx = tid & 15, ty = tid >> 4;
    float acc[4][4] = {};
    for (int k0 = 0; k0 < DR_; k0 += BK) {
        #pragma unroll
        for (int r = 0; r < 4; r++) {
            int j = tid + 256 * r;
            int k = j & 15, m = j >> 4;
            sA[k][m] = A[(size_t)(bm + m) * DR_ + k0 + k];
        }
        #pragma unroll
        for (int r = 0; r < 4; r++) {
            int j = tid + 256 * r;
            int k = j & 15, n = j >> 4;
            sW[k][n] = W[(size_t)(bn + n) * DR_ + k0 + k];
        }
        __syncthreads();
        #pragma unroll
        for (int k = 0; k < BK; k++) {
            float a[4], w[4];
            #pragma unroll
            for (int i = 0; i < 4; i++) a[i] = sA[k][ty * 4 + i];
            #pragma unroll
            for (int j = 0; j < 4; j++) w[j] = sW[k][tx * 4 + j];
            #pragma unroll
            for (int i = 0; i < 4; i++)
                #pragma unroll
                for (int j = 0; j < 4; j++)
                    acc[i][j] += a[i] * w[j];
        }
        __syncthreads();
    }
    #pragma unroll
    for (int i = 0; i < 4; i++) {
        int m = bm + ty * 4 + i;
        #pragma unroll
        for (int j = 0; j < 4; j++) {
            int n = bn + tx * 4 + j;
            float v = acc[i][j] + bias[n];
            v = (v > 20.f) ? v : log1pf(__expf(v));
            dtxc[((size_t)m * DI_ + n) * 2] = v;   // .x slot
        }
    }
}

// ---------------- causal depthwise conv (K=4) + bias + SiLU -----------------
// writes xc into dtxc[...].y (scan) and bf16 xcb (x_proj GEMM operand)
__global__ void conv_silu_kernel(const float* __restrict__ xz,
                                 const float* __restrict__ cw,
                                 const float* __restrict__ cb,
                                 float* __restrict__ dtxc,
                                 unsigned short* __restrict__ xcb) {
    int idx = blockIdx.x * blockDim.x + threadIdx.x;   // over B*L*DI
    if (idx >= B_ * L_ * DI_) return;
    int d = idx % DI_;
    int t = (idx / DI_) % L_;
    int b = idx / (DI_ * L_);
    float acc = cb[d];
    #pragma unroll
    for (int k = 0; k < KC_; k++) {
        int tt = t + k - (KC_ - 1);
        if (tt >= 0)
            acc += xz[((size_t)(b * L_ + tt)) * (2 * DI_) + d] * cw[d * KC_ + k];
    }
    float v = acc / (1.0f + __expf(-acc));
    dtxc[(size_t)idx * 2 + 1] = v;   // .y slot
    xcb[idx] = f2bf(v);
}

// ---------------- scan pass 1: per-chunk decay product + local endpoint -----
__global__ __launch_bounds__(256) void scan_part1(
    const float2* __restrict__ dtxc,   // (B*L, DI) {dt, xc}
    const float2* __restrict__ bcp,    // (B*L, 16) {B_n, C_n}
    const float* __restrict__ A_log,
    float* __restrict__ Pbuf, float* __restrict__ Sbuf) {
    int lane = threadIdx.x & 15;
    int grp = (blockIdx.x * 256 + threadIdx.x) >> 4;   // b*NC*DI + c*DI + d
    int d = grp % DI_;
    int c = (grp / DI_) % NC_;
    int b = grp / (DI_ * NC_);
    float A = -__expf(A_log[d * NS_ + lane]);
    float h = 0.f, sd = 0.f;
    int t0 = c * T_;
    #pragma unroll 4
    for (int t = t0; t < t0 + T_; t++) {
        size_t bt = (size_t)(b * L_ + t);
        float2 dx = dtxc[bt * DI_ + d];
        float2 bc = bcp[bt * 16 + lane];
        h = __expf(dx.x * A) * h + dx.x * dx.y * bc.x;
        sd += dx.x;
    }
    size_t o = (((size_t)b * NC_ + c) * DI_ + d) * NS_ + lane;
    Pbuf[o] = __expf(A * sd);
    Sbuf[o] = h;
}

// ---------------- scan pass 2: sequential combine over chunks ---------------
__global__ __launch_bounds__(256) void scan_part2(
    const float* __restrict__ P, const float* __restrict__ S,
    float* __restrict__ hin) {
    int i = blockIdx.x * 256 + threadIdx.x;   // over B*DI*NS
    int b = i / (DI_ * NS_);
    int rem = i % (DI_ * NS_);
    float h = 0.f;
    #pragma unroll
    for (int c = 0; c < NC_; c++) {
        size_t o = ((size_t)b * NC_ + c) * (DI_ * NS_) + rem;
        hin[o] = h;
        h = P[o] * h + S[o];
    }
}

// ---------------- scan pass 3: rescan chunk with init state, gate, bf16 out -
__global__ __launch_bounds__(256) void scan_part3(
    const float2* __restrict__ dtxc, const float2* __restrict__ bcp,
    const float* __restrict__ xz,
    const float* __restrict__ A_log, const float* __restrict__ Dp,
    const float* __restrict__ hin, unsigned short* __restrict__ yg) {
    int lane = threadIdx.x & 15;
    int grp = (blockIdx.x * 256 + threadIdx.x) >> 4;
    int d = grp % DI_;
    int c = (grp / DI_) % NC_;
    int b = grp / (DI_ * NC_);
    float A = -__expf(A_log[d * NS_ + lane]);
    float Dv = Dp[d];
    float h = hin[(((size_t)b * NC_ + c) * DI_ + d) * NS_ + lane];
    int t0 = c * T_;
    #pragma unroll 4
    for (int t = t0; t < t0 + T_; t++) {
        size_t bt = (size_t)(b * L_ + t);
        float2 dx = dtxc[bt * DI_ + d];
        float2 bc = bcp[bt * 16 + lane];
        h = __expf(dx.x * A) * h + dx.x * dx.y * bc.x;
        float y = h * bc.y;
        y += __shfl_xor(y, 1);
        y += __shfl_xor(y, 2);
        y += __shfl_xor(y, 4);
        y += __shfl_xor(y, 8);
        if (lane == 0) {
            float zv = xz[bt * (2 * DI_) + DI_ + d];
            float yy = y + dx.y * Dv;
            yy *= zv / (1.0f + __expf(-zv));
            yg[bt * DI_ + d] = f2bf(yy);
        }
    }
}

extern "C" void kernel_launch(void* const* d_in, const int* in_sizes, int n_in,
                              void* d_out, int out_size, void* d_ws, size_t ws_size,
                              hipStream_t stream) {
    const float* x        = (const float*)d_in[0];
    const float* ln_w     = (const float*)d_in[1];
    const float* ln_b     = (const float*)d_in[2];
    const float* in_proj  = (const float*)d_in[3];
    const float* conv_w   = (const float*)d_in[4];
    const float* conv_b   = (const float*)d_in[5];
    const float* x_proj   = (const float*)d_in[6];
    const float* dt_w     = (const float*)d_in[7];
    const float* dt_b     = (const float*)d_in[8];
    const float* A_log    = (const float*)d_in[9];
    const float* D_skip   = (const float*)d_in[10];
    const float* out_proj = (const float*)d_in[11];
    const float* fn_w     = (const float*)d_in[12];
    const float* fn_b     = (const float*)d_in[13];
    float* out = (float*)d_out;

    char* p = (char*)d_ws;
    auto alloc = [&](size_t bytes) {
        char* r = p;
        p += (bytes + 255) & ~(size_t)255;
        return (void*)r;
    };
    float* xcur = (float*)alloc((size_t)M_ * D_ * 4);
    float* res  = (float*)alloc((size_t)M_ * D_ * 4);
    unsigned short* xn = (unsigned short*)alloc((size_t)M_ * D_ * 2);
    float* xz   = (float*)alloc((size_t)M_ * 2 * DI_ * 4);
    unsigned short* xcb = (unsigned short*)alloc((size_t)M_ * DI_ * 2);
    float* dtxc = (float*)alloc((size_t)M_ * DI_ * 2 * 4);   // {dt, xc} pairs
    float* dbcdt = (float*)alloc((size_t)M_ * DR_ * 4);
    float* bcp  = (float*)alloc((size_t)M_ * 32 * 4);        // {B,C} pairs x 16
    unsigned short* yg = (unsigned short*)alloc((size_t)M_ * DI_ * 2);
    float* Pbuf = (float*)alloc((size_t)B_ * NC_ * DI_ * NS_ * 4);
    float* Sbuf = (float*)alloc((size_t)B_ * NC_ * DI_ * NS_ * 4);
    float* hin  = (float*)alloc((size_t)B_ * NC_ * DI_ * NS_ * 4);
    float* Pb   = (float*)alloc((size_t)KS_ * M_ * 80 * 4);
    const size_t n_wi = (size_t)NL_ * 2 * DI_ * D_;   // 18.87M
    const size_t n_wo = (size_t)NL_ * D_ * DI_;       // 9.44M
    const size_t n_wx = (size_t)NL_ * 80 * DI_;       // 0.98M
    unsigned short* wi_bf = (unsigned short*)alloc(n_wi * 2);
    unsigned short* wo_bf = (unsigned short*)alloc(n_wo * 2);
    unsigned short* wx_bf = (unsigned short*)alloc(n_wx * 2);

    convert_bf16_kernel<<<(n_wi + 255) / 256, 256, 0, stream>>>(in_proj, wi_bf, (int)n_wi);
    convert_bf16_kernel<<<(n_wo + 255) / 256, 256, 0, stream>>>(out_proj, wo_bf, (int)n_wo);
    convert_bf16_kernel<<<(n_wx + 255) / 256, 256, 0, stream>>>(x_proj, wx_bf, (int)n_wx);

    init_kernel<<<(M_ * D_ + 255) / 256, 256, 0, stream>>>(x, xcur, res, M_ * D_);

    for (int l = 0; l < NL_; l++) {
        ln_res_kernel<<<M_, 256, 0, stream>>>(
            xcur, res, ln_w + l * D_, ln_b + l * D_, xn);

        // xz = xn @ Wi^T   (M=2048, N=3072, K=768)  bf16 MFMA
        gemm_bf16_kernel<<<dim3((2 * DI_) / 128, M_ / 128), 256, 0, stream>>>(
            xn, wi_bf + (size_t)l * 2 * DI_ * D_, xz, M_, 2 * DI_, D_);

        conv_silu_kernel<<<(B_ * L_ * DI_ + 255) / 256, 256, 0, stream>>>(
            xz, conv_w + l * DI_ * KC_, conv_b + l * DI_, dtxc, xcb);

        // dbc = xcb @ Wx^T  (M=2048, N=80, K=1536)  bf16 MFMA split-K
        xproj_gemm_kernel<<<dim3(KS_, M_ / 64), 256, 0, stream>>>(
            xcb, wx_bf + (size_t)l * 80 * DI_, Pb);
        xproj_reduce_kernel<<<(M_ * 80) / 256, 256, 0, stream>>>(Pb, dbcdt, bcp);

        // dt = softplus(dbcdt @ Wdt^T + bdt) -> dtxc.x  (M=2048, N=1536, K=48)
        dt_gemm_kernel<<<dim3(DI_ / 64, M_ / 64), 256, 0, stream>>>(
            dbcdt, dt_w + (size_t)l * DI_ * DR_, dt_b + l * DI_, dtxc);

        // chunked selective scan
        scan_part1<<<(B_ * NC_ * DI_ * 16) / 256, 256, 0, stream>>>(
            (const float2*)dtxc, (const float2*)bcp,
            A_log + (size_t)l * DI_ * NS_, Pbuf, Sbuf);
        scan_part2<<<(B_ * DI_ * NS_) / 256, 256, 0, stream>>>(Pbuf, Sbuf, hin);
        scan_part3<<<(B_ * NC_ * DI_ * 16) / 256, 256, 0, stream>>>(
            (const float2*)dtxc, (const float2*)bcp, xz,
            A_log + (size_t)l * DI_ * NS_, D_skip + l * DI_, hin, yg);

        // xcur = yg @ Wo^T  (M=2048, N=768, K=1536)  bf16 MFMA
        gemm_bf16_kernel<<<dim3(D_ / 128, M_ / 128), 256, 0, stream>>>(
            yg, wo_bf + (size_t)l * D_ * DI_, xcur, M_, D_, DI_);
    }

    final_ln_kernel<<<M_, 256, 0, stream>>>(xcur, res, fn_w, fn_b, out);
}

// Round 5
// 2035.095 us; speedup vs baseline: 1.1614x; 1.1614x over previous
//
#include <hip/hip_runtime.h>
#include <math.h>

#define B_ 2
#define L_ 1024
#define D_ 768
#define NL_ 8
#define DI_ 1536
#define NS_ 16
#define DR_ 48
#define KC_ 4
#define EPS_ 1e-5f
#define M_ (B_*L_)   // 2048 rows
#define NC_ 8        // scan chunks (6144 waves = single resident batch)
#define T_ 128       // chunk length (NC_*T_ == L_)
#define KS_ 16       // x_proj split-K factor
#define KCH_ (DI_/KS_)   // 96 per split

typedef short bf16x8 __attribute__((ext_vector_type(8)));
typedef float f32x4  __attribute__((ext_vector_type(4)));

// ---------------- fp32 -> bf16 (RNE) ---------------------------------------
__device__ __forceinline__ unsigned short f2bf(float f) {
    union { float f; unsigned int u; } v; v.f = f;
    unsigned int u = v.u;
    u += 0x7fffu + ((u >> 16) & 1u);
    return (unsigned short)(u >> 16);
}

__global__ void convert_bf16_kernel(const float* __restrict__ src,
                                    unsigned short* __restrict__ dst, int n) {
    int i = blockIdx.x * blockDim.x + threadIdx.x;
    if (i < n) dst[i] = f2bf(src[i]);
}

// negA = -exp(A_log), all layers at once
__global__ void negA_kernel(const float* __restrict__ A_log,
                            float* __restrict__ negA, int n) {
    int i = blockIdx.x * blockDim.x + threadIdx.x;
    if (i < n) negA[i] = -__expf(A_log[i]);
}

// ---------------- DPP 16-lane row sum (VALU only, no DS pipe) ---------------
__device__ __forceinline__ float row_sum16(float v) {
    int t;
    t = __builtin_amdgcn_update_dpp(0, __float_as_int(v), 0x128, 0xf, 0xf, false); // row_ror:8
    v += __int_as_float(t);
    t = __builtin_amdgcn_update_dpp(0, __float_as_int(v), 0x124, 0xf, 0xf, false); // row_ror:4
    v += __int_as_float(t);
    t = __builtin_amdgcn_update_dpp(0, __float_as_int(v), 0x122, 0xf, 0xf, false); // row_ror:2
    v += __int_as_float(t);
    t = __builtin_amdgcn_update_dpp(0, __float_as_int(v), 0x121, 0xf, 0xf, false); // row_ror:1
    v += __int_as_float(t);
    return v;
}

// ---------------- block reduction helper (256 threads = 4 waves) ------------
__device__ __forceinline__ float block_sum256(float v) {
    __shared__ float sb[4];
    #pragma unroll
    for (int o = 32; o > 0; o >>= 1) v += __shfl_down(v, o);
    if ((threadIdx.x & 63) == 0) sb[threadIdx.x >> 6] = v;
    __syncthreads();
    float r = sb[0] + sb[1] + sb[2] + sb[3];
    __syncthreads();
    return r;
}

// ---------------- init: xcur = x, res = 0 -----------------------------------
__global__ void init_kernel(const float* __restrict__ x,
                            float* __restrict__ xcur,
                            float* __restrict__ res, int n) {
    int i = blockIdx.x * blockDim.x + threadIdx.x;
    if (i < n) { xcur[i] = x[i]; res[i] = 0.f; }
}

// ---------------- fused residual-accumulate + LayerNorm (bf16 out) ----------
__global__ __launch_bounds__(256) void ln_res_kernel(
    const float* __restrict__ xcur, float* __restrict__ res,
    const float* __restrict__ w, const float* __restrict__ b,
    unsigned short* __restrict__ xn) {
    int row = blockIdx.x;
    int t = threadIdx.x;
    size_t base = (size_t)row * D_;
    float v0 = xcur[base + t];
    float v1 = xcur[base + t + 256];
    float v2 = xcur[base + t + 512];
    res[base + t]       += v0;
    res[base + t + 256] += v1;
    res[base + t + 512] += v2;
    float mu = block_sum256(v0 + v1 + v2) * (1.0f / D_);
    float d0 = v0 - mu, d1 = v1 - mu, d2 = v2 - mu;
    float var = block_sum256(d0 * d0 + d1 * d1 + d2 * d2) * (1.0f / D_);
    float rs = rsqrtf(var + EPS_);
    xn[base + t]       = f2bf(d0 * rs * w[t]       + b[t]);
    xn[base + t + 256] = f2bf(d1 * rs * w[t + 256] + b[t + 256]);
    xn[base + t + 512] = f2bf(d2 * rs * w[t + 512] + b[t + 512]);
}

// ---------------- final LN: out = LN(xcur + res) ----------------------------
__global__ __launch_bounds__(256) void final_ln_kernel(
    const float* __restrict__ xcur, const float* __restrict__ res,
    const float* __restrict__ w, const float* __restrict__ b,
    float* __restrict__ out) {
    int row = blockIdx.x;
    int t = threadIdx.x;
    size_t base = (size_t)row * D_;
    float v0 = xcur[base + t]       + res[base + t];
    float v1 = xcur[base + t + 256] + res[base + t + 256];
    float v2 = xcur[base + t + 512] + res[base + t + 512];
    float mu = block_sum256(v0 + v1 + v2) * (1.0f / D_);
    float d0 = v0 - mu, d1 = v1 - mu, d2 = v2 - mu;
    float var = block_sum256(d0 * d0 + d1 * d1 + d2 * d2) * (1.0f / D_);
    float rs = rsqrtf(var + EPS_);
    out[base + t]       = d0 * rs * w[t]       + b[t];
    out[base + t + 256] = d1 * rs * w[t + 256] + b[t + 256];
    out[base + t + 512] = d2 * rs * w[t + 512] + b[t + 512];
}

// ---------------- bf16 MFMA GEMM: C[M,N] = A[M,K] * W[N,K]^T ---------------
__global__ __launch_bounds__(256) void gemm_bf16_kernel(
    const unsigned short* __restrict__ A,   // M x K bf16 row-major
    const unsigned short* __restrict__ W,   // N x K bf16 row-major
    float* __restrict__ C, int M, int N, int K) {
    __shared__ unsigned short sA[128 * 32];
    __shared__ unsigned short sW[128 * 32];
    int bm = blockIdx.y * 128, bn = blockIdx.x * 128;
    int tid = threadIdx.x;
    int wave = tid >> 6, lane = tid & 63;
    int wrow = (wave & 1) * 64, wcol = (wave >> 1) * 64;
    int quad = lane >> 4, r16 = lane & 15;
    f32x4 acc[4][4];
    #pragma unroll
    for (int i = 0; i < 4; i++)
        #pragma unroll
        for (int j = 0; j < 4; j++)
            acc[i][j] = (f32x4){0.f, 0.f, 0.f, 0.f};

    int srow = tid >> 2;              // 0..63
    int scol = (tid & 3) * 8;         // 0,8,16,24
    for (int k0 = 0; k0 < K; k0 += 32) {
        *(uint4*)&sA[tid * 8] =
            *(const uint4*)&A[(size_t)(bm + srow) * K + k0 + scol];
        *(uint4*)&sA[2048 + tid * 8] =
            *(const uint4*)&A[(size_t)(bm + 64 + srow) * K + k0 + scol];
        *(uint4*)&sW[tid * 8] =
            *(const uint4*)&W[(size_t)(bn + srow) * K + k0 + scol];
        *(uint4*)&sW[2048 + tid * 8] =
            *(const uint4*)&W[(size_t)(bn + 64 + srow) * K + k0 + scol];
        __syncthreads();
        bf16x8 af[4], wf[4];
        #pragma unroll
        for (int i = 0; i < 4; i++)
            af[i] = *(const bf16x8*)&sA[(wrow + i * 16 + r16) * 32 + quad * 8];
        #pragma unroll
        for (int j = 0; j < 4; j++)
            wf[j] = *(const bf16x8*)&sW[(wcol + j * 16 + r16) * 32 + quad * 8];
        #pragma unroll
        for (int i = 0; i < 4; i++)
            #pragma unroll
            for (int j = 0; j < 4; j++)
                acc[i][j] = __builtin_amdgcn_mfma_f32_16x16x32_bf16(
                    af[i], wf[j], acc[i][j], 0, 0, 0);
        __syncthreads();
    }
    #pragma unroll
    for (int i = 0; i < 4; i++) {
        #pragma unroll
        for (int j = 0; j < 4; j++) {
            int col = bn + wcol + j * 16 + r16;
            #pragma unroll
            for (int reg = 0; reg < 4; reg++) {
                int row = bm + wrow + i * 16 + quad * 4 + reg;
                C[(size_t)row * N + col] = acc[i][j][reg];
            }
        }
    }
}

// ---------------- x_proj GEMM: Pb[ks][M][80] partials, bf16 MFMA, split-K ---
__global__ __launch_bounds__(256) void xproj_gemm_kernel(
    const unsigned short* __restrict__ A,   // M x DI bf16 (xcb)
    const unsigned short* __restrict__ W,   // 80 x DI bf16
    float* __restrict__ Pb) {               // KS x M x 80 partials
    __shared__ unsigned short sA[64 * 32];
    __shared__ unsigned short sW[80 * 32];
    int ks = blockIdx.x;
    int bm = blockIdx.y * 64;
    int tid = threadIdx.x;
    int wave = tid >> 6, lane = tid & 63;
    int quad = lane >> 4, r16 = lane & 15;
    f32x4 acc[5];
    #pragma unroll
    for (int j = 0; j < 5; j++) acc[j] = (f32x4){0.f, 0.f, 0.f, 0.f};
    int k0base = ks * KCH_;
    for (int kc = 0; kc < KCH_; kc += 32) {
        int k0 = k0base + kc;
        {
            int row = tid >> 2, off = (tid & 3) * 8;
            *(uint4*)&sA[row * 32 + off] =
                *(const uint4*)&A[(size_t)(bm + row) * DI_ + k0 + off];
            *(uint4*)&sW[row * 32 + off] =
                *(const uint4*)&W[(size_t)row * DI_ + k0 + off];
            if (tid < 64) {
                int c = 256 + tid;
                int row2 = c >> 2, off2 = (c & 3) * 8;
                *(uint4*)&sW[row2 * 32 + off2] =
                    *(const uint4*)&W[(size_t)row2 * DI_ + k0 + off2];
            }
        }
        __syncthreads();
        bf16x8 af = *(const bf16x8*)&sA[(wave * 16 + r16) * 32 + quad * 8];
        #pragma unroll
        for (int j = 0; j < 5; j++) {
            bf16x8 wf = *(const bf16x8*)&sW[(j * 16 + r16) * 32 + quad * 8];
            acc[j] = __builtin_amdgcn_mfma_f32_16x16x32_bf16(af, wf, acc[j], 0, 0, 0);
        }
        __syncthreads();
    }
    #pragma unroll
    for (int j = 0; j < 5; j++) {
        int col = j * 16 + r16;
        #pragma unroll
        for (int reg = 0; reg < 4; reg++) {
            int row = bm + wave * 16 + quad * 4 + reg;
            Pb[((size_t)ks * M_ + row) * 80 + col] = acc[j][reg];
        }
    }
}

// reduce split-K partials; scatter into dbcdt (M x 48) and packed BC (M x 16 float2)
__global__ void xproj_reduce_kernel(const float* __restrict__ Pb,
                                    float* __restrict__ dbcdt,
                                    float* __restrict__ bcp) {
    int i = blockIdx.x * 256 + threadIdx.x;   // over M_*80
    float s = 0.f;
    #pragma unroll
    for (int ks = 0; ks < KS_; ks++) s += Pb[(size_t)ks * (M_ * 80) + i];
    int m = i / 80, col = i % 80;
    if (col < DR_) {
        dbcdt[m * DR_ + col] = s;
    } else if (col < DR_ + NS_) {
        bcp[m * 32 + 2 * (col - DR_)] = s;         // B_n
    } else {
        bcp[m * 32 + 2 * (col - DR_ - NS_) + 1] = s; // C_n
    }
}

// ---------------- dt GEMM (fp32, K=48): writes dt into dtxc[...].x ----------
__global__ __launch_bounds__(256) void dt_gemm_kernel(
    const float* __restrict__ A,          // M x 48 (dbcdt)
    const float* __restrict__ W,          // DI x 48 (dt_w)
    const float* __restrict__ bias,       // DI (dt_b)
    float* __restrict__ dtxc) {           // M x DI x 2, writes slot .x
    const int BM = 64, BN = 64, BK = 16;
    __shared__ float sA[BK][BM + 1];
    __shared__ float sW[BK][BN + 1];
    int bm = blockIdx.y * BM, bn = blockIdx.x * BN;
    int tid = threadIdx.x;
    int tx = tid & 15, ty = tid >> 4;
    float acc[4][4] = {};
    for (int k0 = 0; k0 < DR_; k0 += BK) {
        #pragma unroll
        for (int r = 0; r < 4; r++) {
            int j = tid + 256 * r;
            int k = j & 15, m = j >> 4;
            sA[k][m] = A[(size_t)(bm + m) * DR_ + k0 + k];
        }
        #pragma unroll
        for (int r = 0; r < 4; r++) {
            int j = tid + 256 * r;
            int k = j & 15, n = j >> 4;
            sW[k][n] = W[(size_t)(bn + n) * DR_ + k0 + k];
        }
        __syncthreads();
        #pragma unroll
        for (int k = 0; k < BK; k++) {
            float a[4], w[4];
            #pragma unroll
            for (int i = 0; i < 4; i++) a[i] = sA[k][ty * 4 + i];
            #pragma unroll
            for (int j = 0; j < 4; j++) w[j] = sW[k][tx * 4 + j];
            #pragma unroll
            for (int i = 0; i < 4; i++)
                #pragma unroll
                for (int j = 0; j < 4; j++)
                    acc[i][j] += a[i] * w[j];
        }
        __syncthreads();
    }
    #pragma unroll
    for (int i = 0; i < 4; i++) {
        int m = bm + ty * 4 + i;
        #pragma unroll
        for (int j = 0; j < 4; j++) {
            int n = bn + tx * 4 + j;
            float v = acc[i][j] + bias[n];
            v = (v > 20.f) ? v : log1pf(__expf(v));
            dtxc[((size_t)m * DI_ + n) * 2] = v;   // .x slot
        }
    }
}

// ---------------- causal depthwise conv (K=4) + bias + SiLU -----------------
__global__ void conv_silu_kernel(const float* __restrict__ xz,
                                 const float* __restrict__ cw,
                                 const float* __restrict__ cb,
                                 float* __restrict__ dtxc,
                                 unsigned short* __restrict__ xcb) {
    int idx = blockIdx.x * blockDim.x + threadIdx.x;   // over B*L*DI
    if (idx >= B_ * L_ * DI_) return;
    int d = idx % DI_;
    int t = (idx / DI_) % L_;
    int b = idx / (DI_ * L_);
    float acc = cb[d];
    #pragma unroll
    for (int k = 0; k < KC_; k++) {
        int tt = t + k - (KC_ - 1);
        if (tt >= 0)
            acc += xz[((size_t)(b * L_ + tt)) * (2 * DI_) + d] * cw[d * KC_ + k];
    }
    float v = acc / (1.0f + __expf(-acc));
    dtxc[(size_t)idx * 2 + 1] = v;   // .y slot
    xcb[idx] = f2bf(v);
}

// ---------------- scan pass 1: local scan; store {y_local, cumdt} per t -----
// 16 lanes per (b,c,d) group; lane n = state. DPP reduce, no DS.
__global__ __launch_bounds__(256) void scan_chunk_kernel(
    const float2* __restrict__ dtxc,   // (B*L, DI) {dt, xc}
    const float2* __restrict__ bcp,    // (B*L, 16) {B_n, C_n}
    const float* __restrict__ negA,    // (DI, NS) this layer, -exp(A_log)
    float* __restrict__ Pbuf, float* __restrict__ Sbuf,
    float2* __restrict__ ylcd) {       // (B*L, DI) {y_local, cumdt}
    int lane = threadIdx.x & 15;
    int grp = (blockIdx.x * 256 + threadIdx.x) >> 4;   // b*NC*DI + c*DI + d
    int d = grp % DI_;
    int c = (grp / DI_) % NC_;
    int b = grp / (DI_ * NC_);
    float A = negA[d * NS_ + lane];
    float h = 0.f, sd = 0.f;
    int t0 = c * T_;
    const float2* pdx = dtxc + (size_t)(b * L_ + t0) * DI_ + d;
    const float2* pbc = bcp  + (size_t)(b * L_ + t0) * 16 + lane;
    float2*       pyl = ylcd + (size_t)(b * L_ + t0) * DI_ + d;
    for (int t4 = 0; t4 < T_; t4 += 4) {
        float y[4], cd[4];
        #pragma unroll
        for (int u = 0; u < 4; u++) {
            float2 dx = pdx[u * DI_];
            float2 bc = pbc[u * 16];
            h = __expf(dx.x * A) * h + dx.x * dx.y * bc.x;
            sd += dx.x;
            y[u] = row_sum16(h * bc.y);
            cd[u] = sd;
        }
        if (lane == 0) {
            #pragma unroll
            for (int u = 0; u < 4; u++)
                pyl[u * DI_] = make_float2(y[u], cd[u]);
        }
        pdx += 4 * DI_; pbc += 64; pyl += 4 * DI_;
    }
    size_t o = (((size_t)b * NC_ + c) * DI_ + d) * NS_ + lane;
    Pbuf[o] = __expf(A * sd);
    Sbuf[o] = h;
}

// ---------------- scan pass 2: sequential combine over chunks ---------------
__global__ __launch_bounds__(256) void scan_part2(
    const float* __restrict__ P, const float* __restrict__ S,
    float* __restrict__ hin) {
    int i = blockIdx.x * 256 + threadIdx.x;   // over B*DI*NS
    int b = i / (DI_ * NS_);
    int rem = i % (DI_ * NS_);
    float h = 0.f;
    #pragma unroll
    for (int c = 0; c < NC_; c++) {
        size_t o = ((size_t)b * NC_ + c) * (DI_ * NS_) + rem;
        hin[o] = h;
        h = P[o] * h + S[o];
    }
}

// ---------------- scan pass 3: PARALLEL finalize ----------------------------
// y_t = y_local_t + sum_n C_t[n] * exp(A[n]*cumdt_t) * h_in[n]; skip+gate.
__global__ __launch_bounds__(256) void scan_finalize_kernel(
    const float2* __restrict__ ylcd, const float2* __restrict__ dtxc,
    const float* __restrict__ bcp,    // (B*L, 32) interleaved {B,C}
    const float* __restrict__ xz, const float* __restrict__ negA,
    const float* __restrict__ Dp, const float* __restrict__ hin,
    unsigned short* __restrict__ yg) {
    int idx = blockIdx.x * 256 + threadIdx.x;   // over B*L*DI, d fastest
    int d = idx % DI_;
    int bt = idx / DI_;
    int b = bt / L_;
    int t = bt % L_;
    int c = t / T_;
    float2 yl = ylcd[idx];
    float cd = yl.y;
    const float4* hr4 = (const float4*)(hin + (((size_t)b * NC_ + c) * DI_ + d) * NS_);
    const float4* Ar4 = (const float4*)(negA + (size_t)d * NS_);
    const float4* bc4 = (const float4*)(bcp + (size_t)bt * 32);
    float corr = 0.f;
    #pragma unroll
    for (int q = 0; q < 4; q++) {
        float4 hv = hr4[q];
        float4 av = Ar4[q];
        float4 c0 = bc4[2 * q];       // {B,C,B,C}
        float4 c1 = bc4[2 * q + 1];
        corr += c0.y * __expf(av.x * cd) * hv.x;
        corr += c0.w * __expf(av.y * cd) * hv.y;
        corr += c1.y * __expf(av.z * cd) * hv.z;
        corr += c1.w * __expf(av.w * cd) * hv.w;
    }
    float xv = dtxc[idx].y;
    float zv = xz[(size_t)bt * (2 * DI_) + DI_ + d];
    float yy = yl.x + corr + xv * Dp[d];
    yy *= zv / (1.0f + __expf(-zv));
    yg[idx] = f2bf(yy);
}

extern "C" void kernel_launch(void* const* d_in, const int* in_sizes, int n_in,
                              void* d_out, int out_size, void* d_ws, size_t ws_size,
                              hipStream_t stream) {
    const float* x        = (const float*)d_in[0];
    const float* ln_w     = (const float*)d_in[1];
    const float* ln_b     = (const float*)d_in[2];
    const float* in_proj  = (const float*)d_in[3];
    const float* conv_w   = (const float*)d_in[4];
    const float* conv_b   = (const float*)d_in[5];
    const float* x_proj   = (const float*)d_in[6];
    const float* dt_w     = (const float*)d_in[7];
    const float* dt_b     = (const float*)d_in[8];
    const float* A_log    = (const float*)d_in[9];
    const float* D_skip   = (const float*)d_in[10];
    const float* out_proj = (const float*)d_in[11];
    const float* fn_w     = (const float*)d_in[12];
    const float* fn_b     = (const float*)d_in[13];
    float* out = (float*)d_out;

    char* p = (char*)d_ws;
    auto alloc = [&](size_t bytes) {
        char* r = p;
        p += (bytes + 255) & ~(size_t)255;
        return (void*)r;
    };
    float* xcur = (float*)alloc((size_t)M_ * D_ * 4);
    float* res  = (float*)alloc((size_t)M_ * D_ * 4);
    unsigned short* xn = (unsigned short*)alloc((size_t)M_ * D_ * 2);
    float* xz   = (float*)alloc((size_t)M_ * 2 * DI_ * 4);
    unsigned short* xcb = (unsigned short*)alloc((size_t)M_ * DI_ * 2);
    float* dtxc = (float*)alloc((size_t)M_ * DI_ * 2 * 4);   // {dt, xc} pairs
    float* dbcdt = (float*)alloc((size_t)M_ * DR_ * 4);
    float* bcp  = (float*)alloc((size_t)M_ * 32 * 4);        // {B,C} pairs x 16
    unsigned short* yg = (unsigned short*)alloc((size_t)M_ * DI_ * 2);
    float* Pbuf = (float*)alloc((size_t)B_ * NC_ * DI_ * NS_ * 4);
    float* Sbuf = (float*)alloc((size_t)B_ * NC_ * DI_ * NS_ * 4);
    float* hin  = (float*)alloc((size_t)B_ * NC_ * DI_ * NS_ * 4);
    float* ylcd = (float*)alloc((size_t)M_ * DI_ * 2 * 4);   // {y_local, cumdt}
    float* Pb   = (float*)alloc((size_t)KS_ * M_ * 80 * 4);
    float* negA = (float*)alloc((size_t)NL_ * DI_ * NS_ * 4);
    const size_t n_wi = (size_t)NL_ * 2 * DI_ * D_;   // 18.87M
    const size_t n_wo = (size_t)NL_ * D_ * DI_;       // 9.44M
    const size_t n_wx = (size_t)NL_ * 80 * DI_;       // 0.98M
    unsigned short* wi_bf = (unsigned short*)alloc(n_wi * 2);
    unsigned short* wo_bf = (unsigned short*)alloc(n_wo * 2);
    unsigned short* wx_bf = (unsigned short*)alloc(n_wx * 2);

    convert_bf16_kernel<<<(n_wi + 255) / 256, 256, 0, stream>>>(in_proj, wi_bf, (int)n_wi);
    convert_bf16_kernel<<<(n_wo + 255) / 256, 256, 0, stream>>>(out_proj, wo_bf, (int)n_wo);
    convert_bf16_kernel<<<(n_wx + 255) / 256, 256, 0, stream>>>(x_proj, wx_bf, (int)n_wx);
    negA_kernel<<<(NL_ * DI_ * NS_ + 255) / 256, 256, 0, stream>>>(
        A_log, negA, NL_ * DI_ * NS_);

    init_kernel<<<(M_ * D_ + 255) / 256, 256, 0, stream>>>(x, xcur, res, M_ * D_);

    for (int l = 0; l < NL_; l++) {
        const float* negA_l = negA + (size_t)l * DI_ * NS_;

        ln_res_kernel<<<M_, 256, 0, stream>>>(
            xcur, res, ln_w + l * D_, ln_b + l * D_, xn);

        // xz = xn @ Wi^T   (M=2048, N=3072, K=768)  bf16 MFMA
        gemm_bf16_kernel<<<dim3((2 * DI_) / 128, M_ / 128), 256, 0, stream>>>(
            xn, wi_bf + (size_t)l * 2 * DI_ * D_, xz, M_, 2 * DI_, D_);

        conv_silu_kernel<<<(B_ * L_ * DI_ + 255) / 256, 256, 0, stream>>>(
            xz, conv_w + l * DI_ * KC_, conv_b + l * DI_, dtxc, xcb);

        // dbc = xcb @ Wx^T  (M=2048, N=80, K=1536)  bf16 MFMA split-K
        xproj_gemm_kernel<<<dim3(KS_, M_ / 64), 256, 0, stream>>>(
            xcb, wx_bf + (size_t)l * 80 * DI_, Pb);
        xproj_reduce_kernel<<<(M_ * 80) / 256, 256, 0, stream>>>(Pb, dbcdt, bcp);

        // dt = softplus(dbcdt @ Wdt^T + bdt) -> dtxc.x  (M=2048, N=1536, K=48)
        dt_gemm_kernel<<<dim3(DI_ / 64, M_ / 64), 256, 0, stream>>>(
            dbcdt, dt_w + (size_t)l * DI_ * DR_, dt_b + l * DI_, dtxc);

        // selective scan: one sequential pass + combine + parallel finalize
        scan_chunk_kernel<<<(B_ * NC_ * DI_ * 16) / 256, 256, 0, stream>>>(
            (const float2*)dtxc, (const float2*)bcp, negA_l,
            Pbuf, Sbuf, (float2*)ylcd);
        scan_part2<<<(B_ * DI_ * NS_) / 256, 256, 0, stream>>>(Pbuf, Sbuf, hin);
        scan_finalize_kernel<<<(M_ * DI_) / 256, 256, 0, stream>>>(
            (const float2*)ylcd, (const float2*)dtxc, bcp, xz, negA_l,
            D_skip + (size_t)l * DI_, hin, yg);

        // xcur = yg @ Wo^T  (M=2048, N=768, K=1536)  bf16 MFMA
        gemm_bf16_kernel<<<dim3(D_ / 128, M_ / 128), 256, 0, stream>>>(
            yg, wo_bf + (size_t)l * D_ * DI_, xcur, M_, D_, DI_);
    }

    final_ln_kernel<<<M_, 256, 0, stream>>>(xcur, res, fn_w, fn_b, out);
}

// Round 6
// 2029.856 us; speedup vs baseline: 1.1644x; 1.0026x over previous
//
#include <hip/hip_runtime.h>
#include <math.h>

#define B_ 2
#define L_ 1024
#define D_ 768
#define NL_ 8
#define DI_ 1536
#define NS_ 16
#define DR_ 48
#define KC_ 4
#define EPS_ 1e-5f
#define M_ (B_*L_)   // 2048 rows
#define NC_ 8        // scan chunks (6144 waves = single resident batch)
#define T_ 128       // chunk length (NC_*T_ == L_)
#define KS_ 16       // x_proj split-K factor
#define KCH_ (DI_/KS_)   // 96 per split

typedef short bf16x8 __attribute__((ext_vector_type(8)));
typedef float f32x4  __attribute__((ext_vector_type(4)));

// ---------------- fp32 -> bf16 (RNE) ---------------------------------------
__device__ __forceinline__ unsigned short f2bf(float f) {
    union { float f; unsigned int u; } v; v.f = f;
    unsigned int u = v.u;
    u += 0x7fffu + ((u >> 16) & 1u);
    return (unsigned short)(u >> 16);
}

// one dispatch: all weight converts + negA + init (saves 4 launch gaps)
__global__ void prep_kernel(const float* __restrict__ wi, unsigned short* __restrict__ wi_bf, int n0,
                            const float* __restrict__ wo, unsigned short* __restrict__ wo_bf, int n1,
                            const float* __restrict__ wx, unsigned short* __restrict__ wx_bf, int n2,
                            const float* __restrict__ A_log, float* __restrict__ negA, int n3,
                            const float* __restrict__ x, float* __restrict__ xcur,
                            float* __restrict__ res, int n4) {
    int i = blockIdx.x * 256 + threadIdx.x;
    if (i < n0) wi_bf[i] = f2bf(wi[i]);
    if (i < n1) wo_bf[i] = f2bf(wo[i]);
    if (i < n2) wx_bf[i] = f2bf(wx[i]);
    if (i < n3) negA[i] = -__expf(A_log[i]);
    if (i < n4) { xcur[i] = x[i]; res[i] = 0.f; }
}

// ---------------- DPP 16-lane row sum (VALU only, no DS pipe) ---------------
__device__ __forceinline__ float row_sum16(float v) {
    int t;
    t = __builtin_amdgcn_update_dpp(0, __float_as_int(v), 0x128, 0xf, 0xf, false); // row_ror:8
    v += __int_as_float(t);
    t = __builtin_amdgcn_update_dpp(0, __float_as_int(v), 0x124, 0xf, 0xf, false); // row_ror:4
    v += __int_as_float(t);
    t = __builtin_amdgcn_update_dpp(0, __float_as_int(v), 0x122, 0xf, 0xf, false); // row_ror:2
    v += __int_as_float(t);
    t = __builtin_amdgcn_update_dpp(0, __float_as_int(v), 0x121, 0xf, 0xf, false); // row_ror:1
    v += __int_as_float(t);
    return v;
}

// ---------------- block reduction helper (256 threads = 4 waves) ------------
__device__ __forceinline__ float block_sum256(float v) {
    __shared__ float sb[4];
    #pragma unroll
    for (int o = 32; o > 0; o >>= 1) v += __shfl_down(v, o);
    if ((threadIdx.x & 63) == 0) sb[threadIdx.x >> 6] = v;
    __syncthreads();
    float r = sb[0] + sb[1] + sb[2] + sb[3];
    __syncthreads();
    return r;
}

// ---------------- fused residual-accumulate + LayerNorm (bf16 out) ----------
__global__ __launch_bounds__(256) void ln_res_kernel(
    const float* __restrict__ xcur, float* __restrict__ res,
    const float* __restrict__ w, const float* __restrict__ b,
    unsigned short* __restrict__ xn) {
    int row = blockIdx.x;
    int t = threadIdx.x;
    size_t base = (size_t)row * D_;
    float v0 = xcur[base + t];
    float v1 = xcur[base + t + 256];
    float v2 = xcur[base + t + 512];
    res[base + t]       += v0;
    res[base + t + 256] += v1;
    res[base + t + 512] += v2;
    float mu = block_sum256(v0 + v1 + v2) * (1.0f / D_);
    float d0 = v0 - mu, d1 = v1 - mu, d2 = v2 - mu;
    float var = block_sum256(d0 * d0 + d1 * d1 + d2 * d2) * (1.0f / D_);
    float rs = rsqrtf(var + EPS_);
    xn[base + t]       = f2bf(d0 * rs * w[t]       + b[t]);
    xn[base + t + 256] = f2bf(d1 * rs * w[t + 256] + b[t + 256]);
    xn[base + t + 512] = f2bf(d2 * rs * w[t + 512] + b[t + 512]);
}

// ---------------- final LN: out = LN(xcur + res) ----------------------------
__global__ __launch_bounds__(256) void final_ln_kernel(
    const float* __restrict__ xcur, const float* __restrict__ res,
    const float* __restrict__ w, const float* __restrict__ b,
    float* __restrict__ out) {
    int row = blockIdx.x;
    int t = threadIdx.x;
    size_t base = (size_t)row * D_;
    float v0 = xcur[base + t]       + res[base + t];
    float v1 = xcur[base + t + 256] + res[base + t + 256];
    float v2 = xcur[base + t + 512] + res[base + t + 512];
    float mu = block_sum256(v0 + v1 + v2) * (1.0f / D_);
    float d0 = v0 - mu, d1 = v1 - mu, d2 = v2 - mu;
    float var = block_sum256(d0 * d0 + d1 * d1 + d2 * d2) * (1.0f / D_);
    float rs = rsqrtf(var + EPS_);
    out[base + t]       = d0 * rs * w[t]       + b[t];
    out[base + t + 256] = d1 * rs * w[t + 256] + b[t + 256];
    out[base + t + 512] = d2 * rs * w[t + 512] + b[t + 512];
}

// ---------------- bf16 MFMA GEMM: C[M,N] = A[M,K] * W[N,K]^T ---------------
__global__ __launch_bounds__(256) void gemm_bf16_kernel(
    const unsigned short* __restrict__ A,   // M x K bf16 row-major
    const unsigned short* __restrict__ W,   // N x K bf16 row-major
    float* __restrict__ C, int M, int N, int K) {
    __shared__ unsigned short sA[128 * 32];
    __shared__ unsigned short sW[128 * 32];
    int bm = blockIdx.y * 128, bn = blockIdx.x * 128;
    int tid = threadIdx.x;
    int wave = tid >> 6, lane = tid & 63;
    int wrow = (wave & 1) * 64, wcol = (wave >> 1) * 64;
    int quad = lane >> 4, r16 = lane & 15;
    f32x4 acc[4][4];
    #pragma unroll
    for (int i = 0; i < 4; i++)
        #pragma unroll
        for (int j = 0; j < 4; j++)
            acc[i][j] = (f32x4){0.f, 0.f, 0.f, 0.f};

    int srow = tid >> 2;              // 0..63
    int scol = (tid & 3) * 8;         // 0,8,16,24
    for (int k0 = 0; k0 < K; k0 += 32) {
        *(uint4*)&sA[tid * 8] =
            *(const uint4*)&A[(size_t)(bm + srow) * K + k0 + scol];
        *(uint4*)&sA[2048 + tid * 8] =
            *(const uint4*)&A[(size_t)(bm + 64 + srow) * K + k0 + scol];
        *(uint4*)&sW[tid * 8] =
            *(const uint4*)&W[(size_t)(bn + srow) * K + k0 + scol];
        *(uint4*)&sW[2048 + tid * 8] =
            *(const uint4*)&W[(size_t)(bn + 64 + srow) * K + k0 + scol];
        __syncthreads();
        bf16x8 af[4], wf[4];
        #pragma unroll
        for (int i = 0; i < 4; i++)
            af[i] = *(const bf16x8*)&sA[(wrow + i * 16 + r16) * 32 + quad * 8];
        #pragma unroll
        for (int j = 0; j < 4; j++)
            wf[j] = *(const bf16x8*)&sW[(wcol + j * 16 + r16) * 32 + quad * 8];
        #pragma unroll
        for (int i = 0; i < 4; i++)
            #pragma unroll
            for (int j = 0; j < 4; j++)
                acc[i][j] = __builtin_amdgcn_mfma_f32_16x16x32_bf16(
                    af[i], wf[j], acc[i][j], 0, 0, 0);
        __syncthreads();
    }
    #pragma unroll
    for (int i = 0; i < 4; i++) {
        #pragma unroll
        for (int j = 0; j < 4; j++) {
            int col = bn + wcol + j * 16 + r16;
            #pragma unroll
            for (int reg = 0; reg < 4; reg++) {
                int row = bm + wrow + i * 16 + quad * 4 + reg;
                C[(size_t)row * N + col] = acc[i][j][reg];
            }
        }
    }
}

// ---------------- x_proj GEMM: Pb[ks][M][80] partials, bf16 MFMA, split-K ---
__global__ __launch_bounds__(256) void xproj_gemm_kernel(
    const unsigned short* __restrict__ A,   // M x DI bf16 (xcb)
    const unsigned short* __restrict__ W,   // 80 x DI bf16
    float* __restrict__ Pb) {               // KS x M x 80 partials
    __shared__ unsigned short sA[64 * 32];
    __shared__ unsigned short sW[80 * 32];
    int ks = blockIdx.x;
    int bm = blockIdx.y * 64;
    int tid = threadIdx.x;
    int wave = tid >> 6, lane = tid & 63;
    int quad = lane >> 4, r16 = lane & 15;
    f32x4 acc[5];
    #pragma unroll
    for (int j = 0; j < 5; j++) acc[j] = (f32x4){0.f, 0.f, 0.f, 0.f};
    int k0base = ks * KCH_;
    for (int kc = 0; kc < KCH_; kc += 32) {
        int k0 = k0base + kc;
        {
            int row = tid >> 2, off = (tid & 3) * 8;
            *(uint4*)&sA[row * 32 + off] =
                *(const uint4*)&A[(size_t)(bm + row) * DI_ + k0 + off];
            *(uint4*)&sW[row * 32 + off] =
                *(const uint4*)&W[(size_t)row * DI_ + k0 + off];
            if (tid < 64) {
                int c = 256 + tid;
                int row2 = c >> 2, off2 = (c & 3) * 8;
                *(uint4*)&sW[row2 * 32 + off2] =
                    *(const uint4*)&W[(size_t)row2 * DI_ + k0 + off2];
            }
        }
        __syncthreads();
        bf16x8 af = *(const bf16x8*)&sA[(wave * 16 + r16) * 32 + quad * 8];
        #pragma unroll
        for (int j = 0; j < 5; j++) {
            bf16x8 wf = *(const bf16x8*)&sW[(j * 16 + r16) * 32 + quad * 8];
            acc[j] = __builtin_amdgcn_mfma_f32_16x16x32_bf16(af, wf, acc[j], 0, 0, 0);
        }
        __syncthreads();
    }
    #pragma unroll
    for (int j = 0; j < 5; j++) {
        int col = j * 16 + r16;
        #pragma unroll
        for (int reg = 0; reg < 4; reg++) {
            int row = bm + wave * 16 + quad * 4 + reg;
            Pb[((size_t)ks * M_ + row) * 80 + col] = acc[j][reg];
        }
    }
}

// reduce split-K partials; scatter into dbcdt (M x 48) and packed BC (M x 16 float2)
__global__ void xproj_reduce_kernel(const float* __restrict__ Pb,
                                    float* __restrict__ dbcdt,
                                    float* __restrict__ bcp) {
    int i = blockIdx.x * 256 + threadIdx.x;   // over M_*80
    float s = 0.f;
    #pragma unroll
    for (int ks = 0; ks < KS_; ks++) s += Pb[(size_t)ks * (M_ * 80) + i];
    int m = i / 80, col = i % 80;
    if (col < DR_) {
        dbcdt[m * DR_ + col] = s;
    } else if (col < DR_ + NS_) {
        bcp[m * 32 + 2 * (col - DR_)] = s;         // B_n
    } else {
        bcp[m * 32 + 2 * (col - DR_ - NS_) + 1] = s; // C_n
    }
}

// ---------------- dt GEMM (fp32, K=48): writes dt into dtxc[...].x ----------
__global__ __launch_bounds__(256) void dt_gemm_kernel(
    const float* __restrict__ A,          // M x 48 (dbcdt)
    const float* __restrict__ W,          // DI x 48 (dt_w)
    const float* __restrict__ bias,       // DI (dt_b)
    float* __restrict__ dtxc) {           // M x DI x 2, writes slot .x
    const int BM = 64, BN = 64, BK = 16;
    __shared__ float sA[BK][BM + 1];
    __shared__ float sW[BK][BN + 1];
    int bm = blockIdx.y * BM, bn = blockIdx.x * BN;
    int tid = threadIdx.x;
    int tx = tid & 15, ty = tid >> 4;
    float acc[4][4] = {};
    for (int k0 = 0; k0 < DR_; k0 += BK) {
        #pragma unroll
        for (int r = 0; r < 4; r++) {
            int j = tid + 256 * r;
            int k = j & 15, m = j >> 4;
            sA[k][m] = A[(size_t)(bm + m) * DR_ + k0 + k];
        }
        #pragma unroll
        for (int r = 0; r < 4; r++) {
            int j = tid + 256 * r;
            int k = j & 15, n = j >> 4;
            sW[k][n] = W[(size_t)(bn + n) * DR_ + k0 + k];
        }
        __syncthreads();
        #pragma unroll
        for (int k = 0; k < BK; k++) {
            float a[4], w[4];
            #pragma unroll
            for (int i = 0; i < 4; i++) a[i] = sA[k][ty * 4 + i];
            #pragma unroll
            for (int j = 0; j < 4; j++) w[j] = sW[k][tx * 4 + j];
            #pragma unroll
            for (int i = 0; i < 4; i++)
                #pragma unroll
                for (int j = 0; j < 4; j++)
                    acc[i][j] += a[i] * w[j];
        }
        __syncthreads();
    }
    #pragma unroll
    for (int i = 0; i < 4; i++) {
        int m = bm + ty * 4 + i;
        #pragma unroll
        for (int j = 0; j < 4; j++) {
            int n = bn + tx * 4 + j;
            float v = acc[i][j] + bias[n];
            v = (v > 20.f) ? v : log1pf(__expf(v));
            dtxc[((size_t)m * DI_ + n) * 2] = v;   // .x slot
        }
    }
}

// ---------------- causal depthwise conv (K=4) + bias + SiLU -----------------
__global__ void conv_silu_kernel(const float* __restrict__ xz,
                                 const float* __restrict__ cw,
                                 const float* __restrict__ cb,
                                 float* __restrict__ dtxc,
                                 unsigned short* __restrict__ xcb) {
    int idx = blockIdx.x * blockDim.x + threadIdx.x;   // over B*L*DI
    if (idx >= B_ * L_ * DI_) return;
    int d = idx % DI_;
    int t = (idx / DI_) % L_;
    int b = idx / (DI_ * L_);
    float acc = cb[d];
    #pragma unroll
    for (int k = 0; k < KC_; k++) {
        int tt = t + k - (KC_ - 1);
        if (tt >= 0)
            acc += xz[((size_t)(b * L_ + tt)) * (2 * DI_) + d] * cw[d * KC_ + k];
    }
    float v = acc / (1.0f + __expf(-acc));
    dtxc[(size_t)idx * 2 + 1] = v;   // .y slot
    xcb[idx] = f2bf(v);
}

// ---------------- scan pass 1: local scan with register double-buffer ------
// 16 lanes per (b,c,d) group; lane n = state. DPP reduce, no DS.
// Prefetch group g+1's 8 loads before computing group g so the vmcnt wait
// lands after ~200 cyc of exp/fma/DPP work instead of before it.
__global__ __launch_bounds__(256) void scan_chunk_kernel(
    const float2* __restrict__ dtxc,   // (B*L, DI) {dt, xc}
    const float2* __restrict__ bcp,    // (B*L, 16) {B_n, C_n}
    const float* __restrict__ negA,    // (DI, NS) this layer, -exp(A_log)
    float* __restrict__ Pbuf, float* __restrict__ Sbuf,
    float2* __restrict__ ylcd) {       // (B*L, DI) {y_local, cumdt}
    int lane = threadIdx.x & 15;
    int grp = (blockIdx.x * 256 + threadIdx.x) >> 4;   // b*NC*DI + c*DI + d
    int d = grp % DI_;
    int c = (grp / DI_) % NC_;
    int b = grp / (DI_ * NC_);
    float A = negA[d * NS_ + lane];
    float h = 0.f, sd = 0.f;
    int t0 = c * T_;
    const float2* pdx = dtxc + (size_t)(b * L_ + t0) * DI_ + d;
    const float2* pbc = bcp  + (size_t)(b * L_ + t0) * 16 + lane;
    float2*       pyl = ylcd + (size_t)(b * L_ + t0) * DI_ + d;

    float2 dxA[4], bcA[4], dxB[4], bcB[4];
    #pragma unroll
    for (int u = 0; u < 4; u++) { dxA[u] = pdx[u * DI_]; bcA[u] = pbc[u * 16]; }

    for (int g = 0; g < T_ / 4; g++) {
        // prefetch next group (loads issue; no wait until the copy at loop end)
        if (g < T_ / 4 - 1) {
            const float2* qdx = pdx + 4 * DI_;
            const float2* qbc = pbc + 64;
            #pragma unroll
            for (int u = 0; u < 4; u++) { dxB[u] = qdx[u * DI_]; bcB[u] = qbc[u * 16]; }
        }
        float y[4], cd[4];
        #pragma unroll
        for (int u = 0; u < 4; u++) {
            float2 dx = dxA[u], bc = bcA[u];
            h = __expf(dx.x * A) * h + dx.x * dx.y * bc.x;
            sd += dx.x;
            y[u] = row_sum16(h * bc.y);
            cd[u] = sd;
        }
        if (lane == 0) {
            #pragma unroll
            for (int u = 0; u < 4; u++)
                pyl[u * DI_] = make_float2(y[u], cd[u]);
        }
        pdx += 4 * DI_; pbc += 64; pyl += 4 * DI_;
        #pragma unroll
        for (int u = 0; u < 4; u++) { dxA[u] = dxB[u]; bcA[u] = bcB[u]; }
    }
    size_t o = (((size_t)b * NC_ + c) * DI_ + d) * NS_ + lane;
    Pbuf[o] = __expf(A * sd);
    Sbuf[o] = h;
}

// ---------------- scan pass 2: sequential combine over chunks ---------------
__global__ __launch_bounds__(256) void scan_part2(
    const float* __restrict__ P, const float* __restrict__ S,
    float* __restrict__ hin) {
    int i = blockIdx.x * 256 + threadIdx.x;   // over B*DI*NS
    int b = i / (DI_ * NS_);
    int rem = i % (DI_ * NS_);
    float h = 0.f;
    #pragma unroll
    for (int c = 0; c < NC_; c++) {
        size_t o = ((size_t)b * NC_ + c) * (DI_ * NS_) + rem;
        hin[o] = h;
        h = P[o] * h + S[o];
    }
}

// ---------------- scan pass 3: PARALLEL finalize ----------------------------
__global__ __launch_bounds__(256) void scan_finalize_kernel(
    const float2* __restrict__ ylcd, const float2* __restrict__ dtxc,
    const float* __restrict__ bcp,    // (B*L, 32) interleaved {B,C}
    const float* __restrict__ xz, const float* __restrict__ negA,
    const float* __restrict__ Dp, const float* __restrict__ hin,
    unsigned short* __restrict__ yg) {
    int idx = blockIdx.x * 256 + threadIdx.x;   // over B*L*DI, d fastest
    int d = idx % DI_;
    int bt = idx / DI_;
    int b = bt / L_;
    int t = bt % L_;
    int c = t / T_;
    float2 yl = ylcd[idx];
    float cd = yl.y;
    const float4* hr4 = (const float4*)(hin + (((size_t)b * NC_ + c) * DI_ + d) * NS_);
    const float4* Ar4 = (const float4*)(negA + (size_t)d * NS_);
    const float4* bc4 = (const float4*)(bcp + (size_t)bt * 32);
    float corr = 0.f;
    #pragma unroll
    for (int q = 0; q < 4; q++) {
        float4 hv = hr4[q];
        float4 av = Ar4[q];
        float4 c0 = bc4[2 * q];       // {B,C,B,C}
        float4 c1 = bc4[2 * q + 1];
        corr += c0.y * __expf(av.x * cd) * hv.x;
        corr += c0.w * __expf(av.y * cd) * hv.y;
        corr += c1.y * __expf(av.z * cd) * hv.z;
        corr += c1.w * __expf(av.w * cd) * hv.w;
    }
    float xv = dtxc[idx].y;
    float zv = xz[(size_t)bt * (2 * DI_) + DI_ + d];
    float yy = yl.x + corr + xv * Dp[d];
    yy *= zv / (1.0f + __expf(-zv));
    yg[idx] = f2bf(yy);
}

extern "C" void kernel_launch(void* const* d_in, const int* in_sizes, int n_in,
                              void* d_out, int out_size, void* d_ws, size_t ws_size,
                              hipStream_t stream) {
    const float* x        = (const float*)d_in[0];
    const float* ln_w     = (const float*)d_in[1];
    const float* ln_b     = (const float*)d_in[2];
    const float* in_proj  = (const float*)d_in[3];
    const float* conv_w   = (const float*)d_in[4];
    const float* conv_b   = (const float*)d_in[5];
    const float* x_proj   = (const float*)d_in[6];
    const float* dt_w     = (const float*)d_in[7];
    const float* dt_b     = (const float*)d_in[8];
    const float* A_log    = (const float*)d_in[9];
    const float* D_skip   = (const float*)d_in[10];
    const float* out_proj = (const float*)d_in[11];
    const float* fn_w     = (const float*)d_in[12];
    const float* fn_b     = (const float*)d_in[13];
    float* out = (float*)d_out;

    char* p = (char*)d_ws;
    auto alloc = [&](size_t bytes) {
        char* r = p;
        p += (bytes + 255) & ~(size_t)255;
        return (void*)r;
    };
    float* xcur = (float*)alloc((size_t)M_ * D_ * 4);
    float* res  = (float*)alloc((size_t)M_ * D_ * 4);
    unsigned short* xn = (unsigned short*)alloc((size_t)M_ * D_ * 2);
    float* xz   = (float*)alloc((size_t)M_ * 2 * DI_ * 4);
    unsigned short* xcb = (unsigned short*)alloc((size_t)M_ * DI_ * 2);
    float* dtxc = (float*)alloc((size_t)M_ * DI_ * 2 * 4);   // {dt, xc} pairs
    float* dbcdt = (float*)alloc((size_t)M_ * DR_ * 4);
    float* bcp  = (float*)alloc((size_t)M_ * 32 * 4);        // {B,C} pairs x 16
    unsigned short* yg = (unsigned short*)alloc((size_t)M_ * DI_ * 2);
    float* Pbuf = (float*)alloc((size_t)B_ * NC_ * DI_ * NS_ * 4);
    float* Sbuf = (float*)alloc((size_t)B_ * NC_ * DI_ * NS_ * 4);
    float* hin  = (float*)alloc((size_t)B_ * NC_ * DI_ * NS_ * 4);
    float* ylcd = (float*)alloc((size_t)M_ * DI_ * 2 * 4);   // {y_local, cumdt}
    float* Pb   = (float*)alloc((size_t)KS_ * M_ * 80 * 4);
    float* negA = (float*)alloc((size_t)NL_ * DI_ * NS_ * 4);
    const size_t n_wi = (size_t)NL_ * 2 * DI_ * D_;   // 18.87M
    const size_t n_wo = (size_t)NL_ * D_ * DI_;       // 9.44M
    const size_t n_wx = (size_t)NL_ * 80 * DI_;       // 0.98M
    unsigned short* wi_bf = (unsigned short*)alloc(n_wi * 2);
    unsigned short* wo_bf = (unsigned short*)alloc(n_wo * 2);
    unsigned short* wx_bf = (unsigned short*)alloc(n_wx * 2);

    // fused prep: weight converts + negA + init (grid sized by largest job)
    prep_kernel<<<(int)((n_wi + 255) / 256), 256, 0, stream>>>(
        in_proj, wi_bf, (int)n_wi,
        out_proj, wo_bf, (int)n_wo,
        x_proj, wx_bf, (int)n_wx,
        A_log, negA, NL_ * DI_ * NS_,
        x, xcur, res, M_ * D_);

    for (int l = 0; l < NL_; l++) {
        const float* negA_l = negA + (size_t)l * DI_ * NS_;

        ln_res_kernel<<<M_, 256, 0, stream>>>(
            xcur, res, ln_w + l * D_, ln_b + l * D_, xn);

        // xz = xn @ Wi^T   (M=2048, N=3072, K=768)  bf16 MFMA
        gemm_bf16_kernel<<<dim3((2 * DI_) / 128, M_ / 128), 256, 0, stream>>>(
            xn, wi_bf + (size_t)l * 2 * DI_ * D_, xz, M_, 2 * DI_, D_);

        conv_silu_kernel<<<(B_ * L_ * DI_ + 255) / 256, 256, 0, stream>>>(
            xz, conv_w + l * DI_ * KC_, conv_b + l * DI_, dtxc, xcb);

        // dbc = xcb @ Wx^T  (M=2048, N=80, K=1536)  bf16 MFMA split-K
        xproj_gemm_kernel<<<dim3(KS_, M_ / 64), 256, 0, stream>>>(
            xcb, wx_bf + (size_t)l * 80 * DI_, Pb);
        xproj_reduce_kernel<<<(M_ * 80) / 256, 256, 0, stream>>>(Pb, dbcdt, bcp);

        // dt = softplus(dbcdt @ Wdt^T + bdt) -> dtxc.x  (M=2048, N=1536, K=48)
        dt_gemm_kernel<<<dim3(DI_ / 64, M_ / 64), 256, 0, stream>>>(
            dbcdt, dt_w + (size_t)l * DI_ * DR_, dt_b + l * DI_, dtxc);

        // selective scan: one sequential pass + combine + parallel finalize
        scan_chunk_kernel<<<(B_ * NC_ * DI_ * 16) / 256, 256, 0, stream>>>(
            (const float2*)dtxc, (const float2*)bcp, negA_l,
            Pbuf, Sbuf, (float2*)ylcd);
        scan_part2<<<(B_ * DI_ * NS_) / 256, 256, 0, stream>>>(Pbuf, Sbuf, hin);
        scan_finalize_kernel<<<(M_ * DI_) / 256, 256, 0, stream>>>(
            (const float2*)ylcd, (const float2*)dtxc, bcp, xz, negA_l,
            D_skip + (size_t)l * DI_, hin, yg);

        // xcur = yg @ Wo^T  (M=2048, N=768, K=1536)  bf16 MFMA
        gemm_bf16_kernel<<<dim3(D_ / 128, M_ / 128), 256, 0, stream>>>(
            yg, wo_bf + (size_t)l * D_ * DI_, xcur, M_, D_, DI_);
    }

    final_ln_kernel<<<M_, 256, 0, stream>>>(xcur, res, fn_w, fn_b, out);
}

// Round 7
// 1725.354 us; speedup vs baseline: 1.3699x; 1.1765x over previous
//
#include <hip/hip_runtime.h>
#include <math.h>

#define B_ 2
#define L_ 1024
#define D_ 768
#define NL_ 8
#define DI_ 1536
#define NS_ 16
#define DR_ 48
#define KC_ 4
#define EPS_ 1e-5f
#define M_ (B_*L_)   // 2048 rows
#define NC_ 64       // scan chunks (thread-per-channel layout)
#define T_ 16        // chunk length (NC_*T_ == L_)
#define KS_ 16       // x_proj split-K factor
#define KCH_ (DI_/KS_)   // 96 per split

typedef short bf16x8 __attribute__((ext_vector_type(8)));
typedef float f32x4  __attribute__((ext_vector_type(4)));

// ---------------- fp32 -> bf16 (RNE) ---------------------------------------
__device__ __forceinline__ unsigned short f2bf(float f) {
    union { float f; unsigned int u; } v; v.f = f;
    unsigned int u = v.u;
    u += 0x7fffu + ((u >> 16) & 1u);
    return (unsigned short)(u >> 16);
}

// one dispatch: all weight converts + negA + init
__global__ void prep_kernel(const float* __restrict__ wi, unsigned short* __restrict__ wi_bf, int n0,
                            const float* __restrict__ wo, unsigned short* __restrict__ wo_bf, int n1,
                            const float* __restrict__ wx, unsigned short* __restrict__ wx_bf, int n2,
                            const float* __restrict__ A_log, float* __restrict__ negA, int n3,
                            const float* __restrict__ x, float* __restrict__ xcur,
                            float* __restrict__ res, int n4) {
    int i = blockIdx.x * 256 + threadIdx.x;
    if (i < n0) wi_bf[i] = f2bf(wi[i]);
    if (i < n1) wo_bf[i] = f2bf(wo[i]);
    if (i < n2) wx_bf[i] = f2bf(wx[i]);
    if (i < n3) negA[i] = -__expf(A_log[i]);
    if (i < n4) { xcur[i] = x[i]; res[i] = 0.f; }
}

// ---------------- block reduction helper (256 threads = 4 waves) ------------
__device__ __forceinline__ float block_sum256(float v) {
    __shared__ float sb[4];
    #pragma unroll
    for (int o = 32; o > 0; o >>= 1) v += __shfl_down(v, o);
    if ((threadIdx.x & 63) == 0) sb[threadIdx.x >> 6] = v;
    __syncthreads();
    float r = sb[0] + sb[1] + sb[2] + sb[3];
    __syncthreads();
    return r;
}

// ---------------- fused residual-accumulate + LayerNorm (bf16 out) ----------
__global__ __launch_bounds__(256) void ln_res_kernel(
    const float* __restrict__ xcur, float* __restrict__ res,
    const float* __restrict__ w, const float* __restrict__ b,
    unsigned short* __restrict__ xn) {
    int row = blockIdx.x;
    int t = threadIdx.x;
    size_t base = (size_t)row * D_;
    float v0 = xcur[base + t];
    float v1 = xcur[base + t + 256];
    float v2 = xcur[base + t + 512];
    res[base + t]       += v0;
    res[base + t + 256] += v1;
    res[base + t + 512] += v2;
    float mu = block_sum256(v0 + v1 + v2) * (1.0f / D_);
    float d0 = v0 - mu, d1 = v1 - mu, d2 = v2 - mu;
    float var = block_sum256(d0 * d0 + d1 * d1 + d2 * d2) * (1.0f / D_);
    float rs = rsqrtf(var + EPS_);
    xn[base + t]       = f2bf(d0 * rs * w[t]       + b[t]);
    xn[base + t + 256] = f2bf(d1 * rs * w[t + 256] + b[t + 256]);
    xn[base + t + 512] = f2bf(d2 * rs * w[t + 512] + b[t + 512]);
}

// ---------------- final LN: out = LN(xcur + res) ----------------------------
__global__ __launch_bounds__(256) void final_ln_kernel(
    const float* __restrict__ xcur, const float* __restrict__ res,
    const float* __restrict__ w, const float* __restrict__ b,
    float* __restrict__ out) {
    int row = blockIdx.x;
    int t = threadIdx.x;
    size_t base = (size_t)row * D_;
    float v0 = xcur[base + t]       + res[base + t];
    float v1 = xcur[base + t + 256] + res[base + t + 256];
    float v2 = xcur[base + t + 512] + res[base + t + 512];
    float mu = block_sum256(v0 + v1 + v2) * (1.0f / D_);
    float d0 = v0 - mu, d1 = v1 - mu, d2 = v2 - mu;
    float var = block_sum256(d0 * d0 + d1 * d1 + d2 * d2) * (1.0f / D_);
    float rs = rsqrtf(var + EPS_);
    out[base + t]       = d0 * rs * w[t]       + b[t];
    out[base + t + 256] = d1 * rs * w[t + 256] + b[t + 256];
    out[base + t + 512] = d2 * rs * w[t + 512] + b[t + 512];
}

// ---------------- bf16 MFMA GEMM: C[M,N] = A[M,K] * W[N,K]^T ---------------
__global__ __launch_bounds__(256) void gemm_bf16_kernel(
    const unsigned short* __restrict__ A,   // M x K bf16 row-major
    const unsigned short* __restrict__ W,   // N x K bf16 row-major
    float* __restrict__ C, int M, int N, int K) {
    __shared__ unsigned short sA[128 * 32];
    __shared__ unsigned short sW[128 * 32];
    int bm = blockIdx.y * 128, bn = blockIdx.x * 128;
    int tid = threadIdx.x;
    int wave = tid >> 6, lane = tid & 63;
    int wrow = (wave & 1) * 64, wcol = (wave >> 1) * 64;
    int quad = lane >> 4, r16 = lane & 15;
    f32x4 acc[4][4];
    #pragma unroll
    for (int i = 0; i < 4; i++)
        #pragma unroll
        for (int j = 0; j < 4; j++)
            acc[i][j] = (f32x4){0.f, 0.f, 0.f, 0.f};

    int srow = tid >> 2;              // 0..63
    int scol = (tid & 3) * 8;         // 0,8,16,24
    for (int k0 = 0; k0 < K; k0 += 32) {
        *(uint4*)&sA[tid * 8] =
            *(const uint4*)&A[(size_t)(bm + srow) * K + k0 + scol];
        *(uint4*)&sA[2048 + tid * 8] =
            *(const uint4*)&A[(size_t)(bm + 64 + srow) * K + k0 + scol];
        *(uint4*)&sW[tid * 8] =
            *(const uint4*)&W[(size_t)(bn + srow) * K + k0 + scol];
        *(uint4*)&sW[2048 + tid * 8] =
            *(const uint4*)&W[(size_t)(bn + 64 + srow) * K + k0 + scol];
        __syncthreads();
        bf16x8 af[4], wf[4];
        #pragma unroll
        for (int i = 0; i < 4; i++)
            af[i] = *(const bf16x8*)&sA[(wrow + i * 16 + r16) * 32 + quad * 8];
        #pragma unroll
        for (int j = 0; j < 4; j++)
            wf[j] = *(const bf16x8*)&sW[(wcol + j * 16 + r16) * 32 + quad * 8];
        #pragma unroll
        for (int i = 0; i < 4; i++)
            #pragma unroll
            for (int j = 0; j < 4; j++)
                acc[i][j] = __builtin_amdgcn_mfma_f32_16x16x32_bf16(
                    af[i], wf[j], acc[i][j], 0, 0, 0);
        __syncthreads();
    }
    #pragma unroll
    for (int i = 0; i < 4; i++) {
        #pragma unroll
        for (int j = 0; j < 4; j++) {
            int col = bn + wcol + j * 16 + r16;
            #pragma unroll
            for (int reg = 0; reg < 4; reg++) {
                int row = bm + wrow + i * 16 + quad * 4 + reg;
                C[(size_t)row * N + col] = acc[i][j][reg];
            }
        }
    }
}

// ---------------- x_proj GEMM: Pb[ks][M][80] partials, bf16 MFMA, split-K ---
__global__ __launch_bounds__(256) void xproj_gemm_kernel(
    const unsigned short* __restrict__ A,   // M x DI bf16 (xcb)
    const unsigned short* __restrict__ W,   // 80 x DI bf16
    float* __restrict__ Pb) {               // KS x M x 80 partials
    __shared__ unsigned short sA[64 * 32];
    __shared__ unsigned short sW[80 * 32];
    int ks = blockIdx.x;
    int bm = blockIdx.y * 64;
    int tid = threadIdx.x;
    int wave = tid >> 6, lane = tid & 63;
    int quad = lane >> 4, r16 = lane & 15;
    f32x4 acc[5];
    #pragma unroll
    for (int j = 0; j < 5; j++) acc[j] = (f32x4){0.f, 0.f, 0.f, 0.f};
    int k0base = ks * KCH_;
    for (int kc = 0; kc < KCH_; kc += 32) {
        int k0 = k0base + kc;
        {
            int row = tid >> 2, off = (tid & 3) * 8;
            *(uint4*)&sA[row * 32 + off] =
                *(const uint4*)&A[(size_t)(bm + row) * DI_ + k0 + off];
            *(uint4*)&sW[row * 32 + off] =
                *(const uint4*)&W[(size_t)row * DI_ + k0 + off];
            if (tid < 64) {
                int c = 256 + tid;
                int row2 = c >> 2, off2 = (c & 3) * 8;
                *(uint4*)&sW[row2 * 32 + off2] =
                    *(const uint4*)&W[(size_t)row2 * DI_ + k0 + off2];
            }
        }
        __syncthreads();
        bf16x8 af = *(const bf16x8*)&sA[(wave * 16 + r16) * 32 + quad * 8];
        #pragma unroll
        for (int j = 0; j < 5; j++) {
            bf16x8 wf = *(const bf16x8*)&sW[(j * 16 + r16) * 32 + quad * 8];
            acc[j] = __builtin_amdgcn_mfma_f32_16x16x32_bf16(af, wf, acc[j], 0, 0, 0);
        }
        __syncthreads();
    }
    #pragma unroll
    for (int j = 0; j < 5; j++) {
        int col = j * 16 + r16;
        #pragma unroll
        for (int reg = 0; reg < 4; reg++) {
            int row = bm + wave * 16 + quad * 4 + reg;
            Pb[((size_t)ks * M_ + row) * 80 + col] = acc[j][reg];
        }
    }
}

// reduce split-K partials; scatter into dbcdt (M x 48) and packed BC (M x 16 float2)
__global__ void xproj_reduce_kernel(const float* __restrict__ Pb,
                                    float* __restrict__ dbcdt,
                                    float* __restrict__ bcp) {
    int i = blockIdx.x * 256 + threadIdx.x;   // over M_*80
    float s = 0.f;
    #pragma unroll
    for (int ks = 0; ks < KS_; ks++) s += Pb[(size_t)ks * (M_ * 80) + i];
    int m = i / 80, col = i % 80;
    if (col < DR_) {
        dbcdt[m * DR_ + col] = s;
    } else if (col < DR_ + NS_) {
        bcp[m * 32 + 2 * (col - DR_)] = s;         // B_n
    } else {
        bcp[m * 32 + 2 * (col - DR_ - NS_) + 1] = s; // C_n
    }
}

// ---------------- dt GEMM (fp32, K=48): writes dt into dtxc[...].x ----------
__global__ __launch_bounds__(256) void dt_gemm_kernel(
    const float* __restrict__ A,          // M x 48 (dbcdt)
    const float* __restrict__ W,          // DI x 48 (dt_w)
    const float* __restrict__ bias,       // DI (dt_b)
    float* __restrict__ dtxc) {           // M x DI x 2, writes slot .x
    const int BM = 64, BN = 64, BK = 16;
    __shared__ float sA[BK][BM + 1];
    __shared__ float sW[BK][BN + 1];
    int bm = blockIdx.y * BM, bn = blockIdx.x * BN;
    int tid = threadIdx.x;
    int tx = tid & 15, ty = tid >> 4;
    float acc[4][4] = {};
    for (int k0 = 0; k0 < DR_; k0 += BK) {
        #pragma unroll
        for (int r = 0; r < 4; r++) {
            int j = tid + 256 * r;
            int k = j & 15, m = j >> 4;
            sA[k][m] = A[(size_t)(bm + m) * DR_ + k0 + k];
        }
        #pragma unroll
        for (int r = 0; r < 4; r++) {
            int j = tid + 256 * r;
            int k = j & 15, n = j >> 4;
            sW[k][n] = W[(size_t)(bn + n) * DR_ + k0 + k];
        }
        __syncthreads();
        #pragma unroll
        for (int k = 0; k < BK; k++) {
            float a[4], w[4];
            #pragma unroll
            for (int i = 0; i < 4; i++) a[i] = sA[k][ty * 4 + i];
            #pragma unroll
            for (int j = 0; j < 4; j++) w[j] = sW[k][tx * 4 + j];
            #pragma unroll
            for (int i = 0; i < 4; i++)
                #pragma unroll
                for (int j = 0; j < 4; j++)
                    acc[i][j] += a[i] * w[j];
        }
        __syncthreads();
    }
    #pragma unroll
    for (int i = 0; i < 4; i++) {
        int m = bm + ty * 4 + i;
        #pragma unroll
        for (int j = 0; j < 4; j++) {
            int n = bn + tx * 4 + j;
            float v = acc[i][j] + bias[n];
            v = (v > 20.f) ? v : log1pf(__expf(v));
            dtxc[((size_t)m * DI_ + n) * 2] = v;   // .x slot
        }
    }
}

// ---------------- causal depthwise conv (K=4) + bias + SiLU -----------------
__global__ void conv_silu_kernel(const float* __restrict__ xz,
                                 const float* __restrict__ cw,
                                 const float* __restrict__ cb,
                                 float* __restrict__ dtxc,
                                 unsigned short* __restrict__ xcb) {
    int idx = blockIdx.x * blockDim.x + threadIdx.x;   // over B*L*DI
    if (idx >= B_ * L_ * DI_) return;
    int d = idx % DI_;
    int t = (idx / DI_) % L_;
    int b = idx / (DI_ * L_);
    float acc = cb[d];
    #pragma unroll
    for (int k = 0; k < KC_; k++) {
        int tt = t + k - (KC_ - 1);
        if (tt >= 0)
            acc += xz[((size_t)(b * L_ + tt)) * (2 * DI_) + d] * cw[d * KC_ + k];
    }
    float v = acc / (1.0f + __expf(-acc));
    dtxc[(size_t)idx * 2 + 1] = v;   // .y slot
    xcb[idx] = f2bf(v);
}

// ---------------- scan pass 1: thread-per-channel, h[16] in registers -------
// Thread owns (b,c,d); 16 independent state chains = high ILP, no DPP, no
// broadcast waste. dtxc/ylcd accesses fully coalesced; bcp row wave-uniform.
__global__ __launch_bounds__(256) void scan_chunk_kernel(
    const float2* __restrict__ dtxc,   // (B*L, DI) {dt, xc}
    const float4* __restrict__ bcp4,   // (B*L, 8) {B0,C0,B1,C1}x4 view
    const float* __restrict__ negA,    // (DI, NS) this layer
    float* __restrict__ Pbuf, float* __restrict__ Sbuf,
    float2* __restrict__ ylcd) {       // (B*L, DI) {y_local, cumdt}
    const int NDB = DI_ / 256;         // 6 d-blocks
    int bx = blockIdx.x;
    int dblk = bx % NDB;
    int c = (bx / NDB) % NC_;
    int b = bx / (NDB * NC_);
    int d = dblk * 256 + threadIdx.x;

    float A[NS_];
    #pragma unroll
    for (int n = 0; n < NS_; n++) A[n] = negA[(size_t)d * NS_ + n];
    float h[NS_];
    #pragma unroll
    for (int n = 0; n < NS_; n++) h[n] = 0.f;
    float sd = 0.f;

    size_t btbase = (size_t)(b * L_ + c * T_);
    const float2* pdx = dtxc + btbase * DI_ + d;
    const float4* pbc = bcp4 + btbase * 8;
    float2*       pyl = ylcd + btbase * DI_ + d;

    #pragma unroll
    for (int t = 0; t < T_; t++) {
        float2 dx = pdx[(size_t)t * DI_];
        float dt = dx.x;
        float u = dt * dx.y;
        sd += dt;
        float y = 0.f;
        #pragma unroll
        for (int q = 0; q < 8; q++) {
            float4 v = pbc[t * 8 + q];     // {B_2q, C_2q, B_2q+1, C_2q+1}
            float e0 = __expf(dt * A[2 * q]);
            h[2 * q] = fmaf(e0, h[2 * q], u * v.x);
            y = fmaf(v.y, h[2 * q], y);
            float e1 = __expf(dt * A[2 * q + 1]);
            h[2 * q + 1] = fmaf(e1, h[2 * q + 1], u * v.z);
            y = fmaf(v.w, h[2 * q + 1], y);
        }
        pyl[(size_t)t * DI_] = make_float2(y, sd);
    }

    size_t o = (((size_t)b * NC_ + c) * DI_ + d) * NS_;
    #pragma unroll
    for (int n = 0; n < NS_; n++) {
        Pbuf[o + n] = __expf(A[n] * sd);
        Sbuf[o + n] = h[n];
    }
}

// ---------------- scan pass 2: sequential combine over chunks ---------------
__global__ __launch_bounds__(256) void scan_part2(
    const float* __restrict__ P, const float* __restrict__ S,
    float* __restrict__ hin) {
    int i = blockIdx.x * 256 + threadIdx.x;   // over B*DI*NS
    int b = i / (DI_ * NS_);
    int rem = i % (DI_ * NS_);
    float h = 0.f;
    for (int c = 0; c < NC_; c++) {
        size_t o = ((size_t)b * NC_ + c) * (DI_ * NS_) + rem;
        hin[o] = h;
        h = P[o] * h + S[o];
    }
}

// ---------------- scan pass 3: PARALLEL finalize ----------------------------
__global__ __launch_bounds__(256) void scan_finalize_kernel(
    const float2* __restrict__ ylcd, const float2* __restrict__ dtxc,
    const float* __restrict__ bcp,    // (B*L, 32) interleaved {B,C}
    const float* __restrict__ xz, const float* __restrict__ negA,
    const float* __restrict__ Dp, const float* __restrict__ hin,
    unsigned short* __restrict__ yg) {
    int idx = blockIdx.x * 256 + threadIdx.x;   // over B*L*DI, d fastest
    int d = idx % DI_;
    int bt = idx / DI_;
    int b = bt / L_;
    int t = bt % L_;
    int c = t / T_;
    float2 yl = ylcd[idx];
    float cd = yl.y;
    const float4* hr4 = (const float4*)(hin + (((size_t)b * NC_ + c) * DI_ + d) * NS_);
    const float4* Ar4 = (const float4*)(negA + (size_t)d * NS_);
    const float4* bc4 = (const float4*)(bcp + (size_t)bt * 32);
    float corr = 0.f;
    #pragma unroll
    for (int q = 0; q < 4; q++) {
        float4 hv = hr4[q];
        float4 av = Ar4[q];
        float4 c0 = bc4[2 * q];       // {B,C,B,C}
        float4 c1 = bc4[2 * q + 1];
        corr += c0.y * __expf(av.x * cd) * hv.x;
        corr += c0.w * __expf(av.y * cd) * hv.y;
        corr += c1.y * __expf(av.z * cd) * hv.z;
        corr += c1.w * __expf(av.w * cd) * hv.w;
    }
    float xv = dtxc[idx].y;
    float zv = xz[(size_t)bt * (2 * DI_) + DI_ + d];
    float yy = yl.x + corr + xv * Dp[d];
    yy *= zv / (1.0f + __expf(-zv));
    yg[idx] = f2bf(yy);
}

extern "C" void kernel_launch(void* const* d_in, const int* in_sizes, int n_in,
                              void* d_out, int out_size, void* d_ws, size_t ws_size,
                              hipStream_t stream) {
    const float* x        = (const float*)d_in[0];
    const float* ln_w     = (const float*)d_in[1];
    const float* ln_b     = (const float*)d_in[2];
    const float* in_proj  = (const float*)d_in[3];
    const float* conv_w   = (const float*)d_in[4];
    const float* conv_b   = (const float*)d_in[5];
    const float* x_proj   = (const float*)d_in[6];
    const float* dt_w     = (const float*)d_in[7];
    const float* dt_b     = (const float*)d_in[8];
    const float* A_log    = (const float*)d_in[9];
    const float* D_skip   = (const float*)d_in[10];
    const float* out_proj = (const float*)d_in[11];
    const float* fn_w     = (const float*)d_in[12];
    const float* fn_b     = (const float*)d_in[13];
    float* out = (float*)d_out;

    char* p = (char*)d_ws;
    auto alloc = [&](size_t bytes) {
        char* r = p;
        p += (bytes + 255) & ~(size_t)255;
        return (void*)r;
    };
    float* xcur = (float*)alloc((size_t)M_ * D_ * 4);
    float* res  = (float*)alloc((size_t)M_ * D_ * 4);
    unsigned short* xn = (unsigned short*)alloc((size_t)M_ * D_ * 2);
    float* xz   = (float*)alloc((size_t)M_ * 2 * DI_ * 4);
    unsigned short* xcb = (unsigned short*)alloc((size_t)M_ * DI_ * 2);
    float* dtxc = (float*)alloc((size_t)M_ * DI_ * 2 * 4);   // {dt, xc} pairs
    float* dbcdt = (float*)alloc((size_t)M_ * DR_ * 4);
    float* bcp  = (float*)alloc((size_t)M_ * 32 * 4);        // {B,C} pairs x 16
    unsigned short* yg = (unsigned short*)alloc((size_t)M_ * DI_ * 2);
    float* Pbuf = (float*)alloc((size_t)B_ * NC_ * DI_ * NS_ * 4);   // 12.6 MB
    float* Sbuf = (float*)alloc((size_t)B_ * NC_ * DI_ * NS_ * 4);
    float* hin  = (float*)alloc((size_t)B_ * NC_ * DI_ * NS_ * 4);
    float* ylcd = (float*)alloc((size_t)M_ * DI_ * 2 * 4);   // {y_local, cumdt}
    float* Pb   = (float*)alloc((size_t)KS_ * M_ * 80 * 4);
    float* negA = (float*)alloc((size_t)NL_ * DI_ * NS_ * 4);
    const size_t n_wi = (size_t)NL_ * 2 * DI_ * D_;   // 18.87M
    const size_t n_wo = (size_t)NL_ * D_ * DI_;       // 9.44M
    const size_t n_wx = (size_t)NL_ * 80 * DI_;       // 0.98M
    unsigned short* wi_bf = (unsigned short*)alloc(n_wi * 2);
    unsigned short* wo_bf = (unsigned short*)alloc(n_wo * 2);
    unsigned short* wx_bf = (unsigned short*)alloc(n_wx * 2);

    // fused prep: weight converts + negA + init (grid sized by largest job)
    prep_kernel<<<(int)((n_wi + 255) / 256), 256, 0, stream>>>(
        in_proj, wi_bf, (int)n_wi,
        out_proj, wo_bf, (int)n_wo,
        x_proj, wx_bf, (int)n_wx,
        A_log, negA, NL_ * DI_ * NS_,
        x, xcur, res, M_ * D_);

    for (int l = 0; l < NL_; l++) {
        const float* negA_l = negA + (size_t)l * DI_ * NS_;

        ln_res_kernel<<<M_, 256, 0, stream>>>(
            xcur, res, ln_w + l * D_, ln_b + l * D_, xn);

        // xz = xn @ Wi^T   (M=2048, N=3072, K=768)  bf16 MFMA
        gemm_bf16_kernel<<<dim3((2 * DI_) / 128, M_ / 128), 256, 0, stream>>>(
            xn, wi_bf + (size_t)l * 2 * DI_ * D_, xz, M_, 2 * DI_, D_);

        conv_silu_kernel<<<(B_ * L_ * DI_ + 255) / 256, 256, 0, stream>>>(
            xz, conv_w + l * DI_ * KC_, conv_b + l * DI_, dtxc, xcb);

        // dbc = xcb @ Wx^T  (M=2048, N=80, K=1536)  bf16 MFMA split-K
        xproj_gemm_kernel<<<dim3(KS_, M_ / 64), 256, 0, stream>>>(
            xcb, wx_bf + (size_t)l * 80 * DI_, Pb);
        xproj_reduce_kernel<<<(M_ * 80) / 256, 256, 0, stream>>>(Pb, dbcdt, bcp);

        // dt = softplus(dbcdt @ Wdt^T + bdt) -> dtxc.x  (M=2048, N=1536, K=48)
        dt_gemm_kernel<<<dim3(DI_ / 64, M_ / 64), 256, 0, stream>>>(
            dbcdt, dt_w + (size_t)l * DI_ * DR_, dt_b + l * DI_, dtxc);

        // selective scan: thread-per-channel local scan + combine + finalize
        scan_chunk_kernel<<<B_ * NC_ * (DI_ / 256), 256, 0, stream>>>(
            (const float2*)dtxc, (const float4*)bcp, negA_l,
            Pbuf, Sbuf, (float2*)ylcd);
        scan_part2<<<(B_ * DI_ * NS_) / 256, 256, 0, stream>>>(Pbuf, Sbuf, hin);
        scan_finalize_kernel<<<(M_ * DI_) / 256, 256, 0, stream>>>(
            (const float2*)ylcd, (const float2*)dtxc, bcp, xz, negA_l,
            D_skip + (size_t)l * DI_, hin, yg);

        // xcur = yg @ Wo^T  (M=2048, N=768, K=1536)  bf16 MFMA
        gemm_bf16_kernel<<<dim3(D_ / 128, M_ / 128), 256, 0, stream>>>(
            yg, wo_bf + (size_t)l * D_ * DI_, xcur, M_, D_, DI_);
    }

    final_ln_kernel<<<M_, 256, 0, stream>>>(xcur, res, fn_w, fn_b, out);
}